// Round 13
// baseline (29118.600 us; speedup 1.0000x reference)
//
#include <hip/hip_runtime.h>
#include <cstddef>

#define TT 4096
#define PP 512
#define WW 1024

using u32 = unsigned;
using u64 = unsigned long long;
using u16 = unsigned short;

typedef short short8 __attribute__((ext_vector_type(8)));
typedef float f32x4 __attribute__((ext_vector_type(4)));

__device__ __forceinline__ u32 bfround(float f) {
    u32 u = __float_as_uint(f);
    return (u + 0x7fffu + ((u >> 16) & 1u)) >> 16;
}
__device__ __forceinline__ float bf2f(u32 q) { return __uint_as_float(q << 16); }
__device__ __forceinline__ float bflo(u32 q) { return __uint_as_float(q << 16); }
__device__ __forceinline__ float bfhi(u32 q) { return __uint_as_float(q & 0xffff0000u); }

#define LDA64(p)    __hip_atomic_load((p),  __ATOMIC_RELAXED, __HIP_MEMORY_SCOPE_AGENT)
#define STA64(p, v) __hip_atomic_store((p), (v), __ATOMIC_RELAXED, __HIP_MEMORY_SCOPE_AGENT)
#define LDA32(p)    __hip_atomic_load((p),  __ATOMIC_RELAXED, __HIP_MEMORY_SCOPE_AGENT)
#define STA32(p, v) __hip_atomic_store((p), (v), __ATOMIC_RELAXED, __HIP_MEMORY_SCOPE_AGENT)
#define STA16(p, v) __hip_atomic_store((p), (v), __ATOMIC_RELAXED, __HIP_MEMORY_SCOPE_AGENT)

// ============ a2bf_t: a[b][t][p] f32 -> abf2[t][p>>3][b][8] bf16 ============
__global__ __launch_bounds__(256, 2) void a2bf_t(const float* __restrict__ a,
                                                 u16* __restrict__ abf2) {
    __shared__ u16 sh[32][528];
    const int t = blockIdx.x, tid = threadIdx.x;
    {
        const int b = tid >> 3, seg = tid & 7;
        const float* ap = &a[((size_t)b * TT + t) * PP + seg * 64];
        #pragma unroll
        for (int j = 0; j < 16; ++j) {
            float4 v = *(const float4*)&ap[j * 4];
            uint2 w;
            w.x = bfround(v.x) | (bfround(v.y) << 16);
            w.y = bfround(v.z) | (bfround(v.w) << 16);
            *(uint2*)&sh[b][seg * 64 + j * 4] = w;
        }
    }
    __syncthreads();
    {
        const int d = tid >> 2, bq = tid & 3;
        #pragma unroll
        for (int bb = 0; bb < 8; ++bb) {
            const int b = bq * 8 + bb;
            uint4 v = *(const uint4*)&sh[b][d * 8];
            *(uint4*)&abf2[(((size_t)t * 64 + d) * 32 + b) * 8] = v;
        }
    }
}

// ============ PREPASS (R12, proven): gWG-owned, parity-dbuf LDS ============
__global__ __launch_bounds__(768, 1) void ig_prepass10(
    const u16* __restrict__ abf2, const float* __restrict__ Wih,
    const float* __restrict__ bias, char* __restrict__ igbase)
{
    __shared__ __align__(8) u16 sIg[2][2][32][48];
    const int gWG = blockIdx.x;
    const int t0  = blockIdx.y * 128;
    const int tid = threadIdx.x;
    const int lane = tid & 63;
    const int wid  = tid >> 6;
    const int tpar = wid / 6;
    const int t6   = wid % 6;
    const int st   = t6 >> 1;
    const int bh   = t6 & 1;
    const int lq   = lane >> 4;
    const int bcol = lane & 15;

    short8 af[16];
    float  bi[4];
    {
        const float* wr = &Wih[(size_t)(st * WW + gWG * 16 + bcol) * PP + lq * 8];
        #pragma unroll
        for (int s = 0; s < 16; ++s) {
            float t8[8];
            *(float4*)&t8[0] = *(const float4*)&wr[s * 32];
            *(float4*)&t8[4] = *(const float4*)&wr[s * 32 + 4];
            #pragma unroll
            for (int j = 0; j < 8; ++j) af[s][j] = (short)bfround(t8[j]);
        }
        #pragma unroll
        for (int r = 0; r < 4; ++r) bi[r] = bias[st * WW + gWG * 16 + lq * 4 + r];
    }

    for (int it = 0; it < 64; ++it) {
        const int par = it & 1;
        const int t = t0 + it * 2 + tpar;
        const u16* bp = &abf2[(((size_t)t * 64 + lq) * 32 + (bh * 16 + bcol)) * 8];
        f32x4 d = {0.f, 0.f, 0.f, 0.f};
        #pragma unroll 4
        for (int s = 0; s < 16; ++s) {
            short8 bf = *(const short8*)&bp[(size_t)s * 4 * 256];
            d = __builtin_amdgcn_mfma_f32_16x16x32_bf16(af[s], bf, d, 0, 0, 0);
        }
        u32 lo = bfround(d[0] + bi[0]) | (bfround(d[1] + bi[1]) << 16);
        u32 hi = bfround(d[2] + bi[2]) | (bfround(d[3] + bi[3]) << 16);
        *(u64*)&sIg[par][tpar][bh * 16 + bcol][st * 16 + lq * 4] = (u64)lo | ((u64)hi << 32);
        __syncthreads();
        {
            const int tp2 = tid / 384;
            const int off = tid - tp2 * 384;
            const int tt  = t0 + it * 2 + tp2;
            ((u64*)(igbase + ((size_t)tt * 64 + gWG) * 3072))[off] =
                ((const u64*)&sIg[par][tp2][0][0])[off];
        }
    }
}

// ============ PREPASS v2 (mid-tier, f32 a, proven) ============
__global__ __launch_bounds__(768, 1) void ig_prepass16(
    const float* __restrict__ a, const float* __restrict__ Wih,
    const float* __restrict__ bias, char* __restrict__ igbase)
{
    const int gp   = blockIdx.x;
    const int t0   = blockIdx.y * 64;
    const int tid  = threadIdx.x;
    const int lane = tid & 63;
    const int wid  = tid >> 6;
    const int growb = gp * 192 + wid * 16;

    short8 afrag[16];
    float  biasv[4];
    {
        const float* wr = &Wih[(size_t)(growb + (lane & 15)) * PP + (lane >> 4) * 8];
        #pragma unroll
        for (int s = 0; s < 16; ++s) {
            float t8[8];
            *(float4*)&t8[0] = *(const float4*)&wr[s * 32];
            *(float4*)&t8[4] = *(const float4*)&wr[s * 32 + 4];
            #pragma unroll
            for (int j = 0; j < 8; ++j) afrag[s][j] = (short)bfround(t8[j]);
        }
        #pragma unroll
        for (int r = 0; r < 4; ++r) biasv[r] = bias[growb + (lane >> 4) * 4 + r];
    }
    const int grow0 = growb + (lane >> 4) * 4;
    const int gate  = grow0 >> 10;
    const int w     = grow0 & 1023;
    const int gWG   = w >> 4;
    const int slot  = gate * 16 + (w & 15);
    const int bcol  = lane & 15;

    for (int ct = 0; ct < 128; ++ct) {
        const int t = t0 + (ct >> 1);
        const int b = (ct & 1) * 16 + bcol;
        const float* ap = &a[((size_t)b * TT + t) * PP + (lane >> 4) * 8];
        f32x4 d = {0.f, 0.f, 0.f, 0.f};
        #pragma unroll 4
        for (int s = 0; s < 16; ++s) {
            float4 lo = *(const float4*)&ap[s * 32];
            float4 hi = *(const float4*)&ap[s * 32 + 4];
            short8 bfv;
            bfv[0] = (short)((__float_as_uint(lo.x) + 0x8000u) >> 16);
            bfv[1] = (short)((__float_as_uint(lo.y) + 0x8000u) >> 16);
            bfv[2] = (short)((__float_as_uint(lo.z) + 0x8000u) >> 16);
            bfv[3] = (short)((__float_as_uint(lo.w) + 0x8000u) >> 16);
            bfv[4] = (short)((__float_as_uint(hi.x) + 0x8000u) >> 16);
            bfv[5] = (short)((__float_as_uint(hi.y) + 0x8000u) >> 16);
            bfv[6] = (short)((__float_as_uint(hi.z) + 0x8000u) >> 16);
            bfv[7] = (short)((__float_as_uint(hi.w) + 0x8000u) >> 16);
            d = __builtin_amdgcn_mfma_f32_16x16x32_bf16(afrag[s], bfv, d, 0, 0, 0);
        }
        u32 lo32 = bfround(d[0] + biasv[0]) | (bfround(d[1] + biasv[1]) << 16);
        u32 hi32 = bfround(d[2] + biasv[2]) | (bfround(d[3] + biasv[3]) << 16);
        *(u64*)(igbase + (((size_t)t * 64 + gWG) * 1536 + (size_t)b * 48 + slot) * 2) =
            (u64)lo32 | ((u64)hi32 << 32);
    }
}

// ============ SCAN v7: two independent 16-batch chains, time-shared per WG ============
// Chain c handles batches c*16..c*16+15. Exchange per chain: u16 idx =
// (k8*16 + gb)*8 + (w&7), k8 = w>>3 -> consumer's per-kslice wave load is
// 1024B contiguous. Flags: 4/WG/chain. Latency of chain A hides under chain B.
__global__ __launch_bounds__(768, 1) void gru_scan7(
    const float* __restrict__ h0v, const float* __restrict__ Whh,
    const float* __restrict__ bias_n, const float* __restrict__ Wout,
    const float* __restrict__ bout, const char* __restrict__ igbase,
    float* __restrict__ out,
    u64* __restrict__ bufA0, u64* __restrict__ bufA1,
    u64* __restrict__ bufB0, u64* __restrict__ bufB1,
    u32* __restrict__ flagsA, u32* __restrict__ flagsB)
{
    __shared__ float sPreH[8][48][17];
    __shared__ float sOutP[4][16][18];
    __shared__ __align__(8) u64 sIgRaw[384];

    const int g    = blockIdx.x;
    const int tid  = threadIdx.x;
    const int lane = tid & 63;
    const int wid  = tid >> 6;
    const int p0   = (g >> 1) * 16;
    const int cp3  = g & 1;                  // chain whose p3 this WG owns

    // weights in registers: hh waves 0-7 (kslices wid*4..+3, 3 gates);
    // p3 waves 8-11 (kslices (wid-8)*8..+7 of Wout)
    short8 frag[12];
    if (wid < 8) {
        #pragma unroll
        for (int gate = 0; gate < 3; ++gate)
            #pragma unroll
            for (int s = 0; s < 4; ++s) {
                const int ss = wid * 4 + s;
                const float* wr = &Whh[(size_t)(gate * WW + g * 16 + (lane & 15)) * WW
                                       + ss * 32 + (lane >> 4) * 8];
                float t8[8];
                *(float4*)&t8[0] = *(const float4*)&wr[0];
                *(float4*)&t8[4] = *(const float4*)&wr[4];
                short8 v;
                #pragma unroll
                for (int j = 0; j < 8; ++j) v[j] = (short)bfround(t8[j]);
                frag[gate * 4 + s] = v;
            }
    } else {
        #pragma unroll
        for (int s = 0; s < 8; ++s) {
            const int ss = (wid - 8) * 8 + s;
            const float* wr = &Wout[(size_t)(p0 + (lane & 15)) * WW + ss * 32 + (lane >> 4) * 8];
            float t8[8];
            *(float4*)&t8[0] = *(const float4*)&wr[0];
            *(float4*)&t8[4] = *(const float4*)&wr[4];
            short8 v;
            #pragma unroll
            for (int j = 0; j < 8; ++j) v[j] = (short)bfround(t8[j]);
            frag[s] = v;
        }
    }

    // gate threads (256..511): one (w,b) cell per chain
    const bool isGate = (tid >= 256 && tid < 512);
    const int idx = tid - 256;
    const int gwl = idx & 15, gb = idx >> 4;          // gb in [0,16)
    float hA = 0.f, hB = 0.f, bnv = 0.f;
    u32 pidx = 0;
    if (isGate) {
        const int w_abs = g * 16 + gwl;
        hA = h0v[w_abs]; hB = hA;
        bnv = bias_n[w_abs];
        pidx = (u32)((((w_abs >> 3) * 16) + gb) * 8 + (w_abs & 7));
        STA16(&((u16*)bufA0)[pidx], (u16)bfround(hA));
        STA16(&((u16*)bufB0)[pidx], (u16)bfround(hB));
    }
    if (wid >= 4 && wid < 8) {
        asm volatile("s_waitcnt vmcnt(0)" ::: "memory");
        if (lane == 0) {
            STA32(&flagsA[g * 16 + (wid - 4)], 1u);
            STA32(&flagsB[g * 16 + (wid - 4)], 1u);
        }
    }
    const float boutp = (tid < 256) ? bout[p0 + (tid & 15)] : 0.f;

    auto poll = [&](u32* flg, u32 want) {
        for (;;) {
            u64 f0 = LDA64((const u64*)&flg[lane * 16]);
            u64 f1 = LDA64((const u64*)&flg[lane * 16 + 2]);
            const u32 a0 = (u32)f0, a1 = (u32)(f0 >> 32);
            const u32 a2 = (u32)f1, a3 = (u32)(f1 >> 32);
            const bool ok = ((int)(a0 - want) >= 0) && ((int)(a1 - want) >= 0) &&
                            ((int)(a2 - want) >= 0) && ((int)(a3 - want) >= 0);
            if (__all(ok)) break;
            __builtin_amdgcn_s_sleep(1);
        }
        asm volatile("" ::: "memory");
    };

    auto hh = [&](const u64* cur) {   // waves 0-7
        f32x4 c0 = {0.f,0.f,0.f,0.f}, c1 = {0.f,0.f,0.f,0.f}, c2 = {0.f,0.f,0.f,0.f};
        #pragma unroll
        for (int s = 0; s < 4; ++s) {
            const int ss = wid * 4 + s;
            const int base = 2 * (ss * 64 + (lane >> 4) * 16 + (lane & 15));
            const u64 q0 = LDA64(&cur[base]);
            const u64 q1 = LDA64(&cur[base + 1]);
            union { u64 q[2]; short8 v; } uu; uu.q[0] = q0; uu.q[1] = q1;
            c0 = __builtin_amdgcn_mfma_f32_16x16x32_bf16(frag[s],     uu.v, c0, 0, 0, 0);
            c1 = __builtin_amdgcn_mfma_f32_16x16x32_bf16(frag[4 + s], uu.v, c1, 0, 0, 0);
            c2 = __builtin_amdgcn_mfma_f32_16x16x32_bf16(frag[8 + s], uu.v, c2, 0, 0, 0);
        }
        const int r0 = (lane >> 4) * 4, col = lane & 15;
        #pragma unroll
        for (int r = 0; r < 4; ++r) {
            sPreH[wid][r0 + r][col]      = c0[r];
            sPreH[wid][16 + r0 + r][col] = c1[r];
            sPreH[wid][32 + r0 + r][col] = c2[r];
        }
    };

    auto p3c = [&](const u64* cur) {  // waves 8-11
        f32x4 d = {0.f, 0.f, 0.f, 0.f};
        #pragma unroll
        for (int s = 0; s < 8; ++s) {
            const int ss = (wid - 8) * 8 + s;
            const int base = 2 * (ss * 64 + (lane >> 4) * 16 + (lane & 15));
            const u64 q0 = LDA64(&cur[base]);
            const u64 q1 = LDA64(&cur[base + 1]);
            union { u64 q[2]; short8 v; } uu; uu.q[0] = q0; uu.q[1] = q1;
            d = __builtin_amdgcn_mfma_f32_16x16x32_bf16(frag[s], uu.v, d, 0, 0, 0);
        }
        const int r0 = (lane >> 4) * 4, col = lane & 15;
        #pragma unroll
        for (int r = 0; r < 4; ++r) sOutP[wid - 8][r0 + r][col] = d[r];
    };

    auto gates = [&](u64* nxt, float& h_own, int bb, int cb, bool p3own,
                     u32* flg, u32 kkflag, int t) {
        if (isGate) {
            const u16* sIgU = (const u16*)sIgRaw;
            const float ig_r = bf2f(sIgU[bb * 48 + gwl]);
            const float ig_z = bf2f(sIgU[bb * 48 + 16 + gwl]);
            const float ig_n = bf2f(sIgU[bb * 48 + 32 + gwl]);
            float hg_r = 0.f, hg_z = 0.f, hg_n = 0.f;
            #pragma unroll
            for (int qz = 0; qz < 8; ++qz) {
                hg_r += sPreH[qz][gwl][gb];
                hg_z += sPreH[qz][16 + gwl][gb];
                hg_n += sPreH[qz][32 + gwl][gb];
            }
            const float rr = __builtin_amdgcn_rcpf(1.f + __expf(-(ig_r + hg_r)));
            const float zz = __builtin_amdgcn_rcpf(1.f + __expf(-(ig_z + hg_z)));
            const float xn = ig_n + rr * (hg_n + bnv);
            const float nn = 2.f * __builtin_amdgcn_rcpf(1.f + __expf(-2.f * xn)) - 1.f;
            h_own = nn + zz * (h_own - nn);
            STA16(&((u16*)nxt)[pidx], (u16)bfround(h_own));
        } else if (tid < 256 && p3own && t < TT - 1) {
            const int p = tid & 15, b = tid >> 4;
            const float s_ = boutp + sOutP[0][p][b] + sOutP[1][p][b]
                                   + sOutP[2][p][b] + sOutP[3][p][b];
            out[((size_t)(cb + b) * TT + (t + 1)) * PP + p0 + p] = s_;
        }
        if (wid >= 4 && wid < 8) {
            asm volatile("s_waitcnt vmcnt(0)" ::: "memory");
            if (lane == 0) STA32(&flg[g * 16 + (wid - 4)], kkflag);
        }
    };

    u64 *curA = bufA0, *nxtA = bufA1, *curB = bufB0, *nxtB = bufB1;
    u32 kk = 1;

    for (int t = TT - 1; t >= 0; --t) {
        u64 igr = 0;
        if (tid < 384) igr = *(const u64*)(igbase + ((size_t)t * 64 + g) * 3072 + tid * 8);

        // ===== phase A (batches 0-15) =====
        poll(flagsA, kk);
        if (wid < 8) hh(curA);
        else if (cp3 == 0 && t < TT - 1) p3c(curA);
        if (tid < 384) sIgRaw[tid] = igr;
        __syncthreads();
        gates(nxtA, hA, gb, 0, cp3 == 0, flagsA, kk + 1, t);
        __syncthreads();

        // ===== phase B (batches 16-31) =====
        poll(flagsB, kk);
        if (wid < 8) hh(curB);
        else if (cp3 == 1 && t < TT - 1) p3c(curB);
        __syncthreads();
        gates(nxtB, hB, 16 + gb, 16, cp3 == 1, flagsB, kk + 1, t);
        __syncthreads();

        u64* tm;
        tm = curA; curA = nxtA; nxtA = tm;
        tm = curB; curB = nxtB; nxtB = tm;
        ++kk;
    }

    // ---- epilogue: s_0 -> out[:,0,:] (each WG: its p-tile, chain cp3) ----
    {
        u64* cure = cp3 ? curB : curA;
        u32* flge = cp3 ? flagsB : flagsA;
        poll(flge, kk);
        if (wid >= 8) p3c(cure);
        __syncthreads();
        if (tid < 256) {
            const int p = tid & 15, b = tid >> 4;
            const float s_ = boutp + sOutP[0][p][b] + sOutP[1][p][b]
                                   + sOutP[2][p][b] + sOutP[3][p][b];
            out[((size_t)(cp3 * 16 + b) * TT) * PP + p0 + p] = s_;
        }
    }
}

// ===================== FALLBACK (proven R3 kernel, 256 WGs) =====================
__device__ __forceinline__ void grid_barrier32(u32* leaf, u32* root, u32 rtarget, int g) {
    asm volatile("s_waitcnt vmcnt(0)" ::: "memory");
    __syncthreads();
    if (threadIdx.x == 0) {
        u32 old = __hip_atomic_fetch_add(&leaf[(g & 7) * 16], 1u,
                                         __ATOMIC_RELAXED, __HIP_MEMORY_SCOPE_AGENT);
        if ((old & 31u) == 31u)
            __hip_atomic_fetch_add(root, 1u, __ATOMIC_RELAXED, __HIP_MEMORY_SCOPE_AGENT);
        while (__hip_atomic_load(root, __ATOMIC_RELAXED, __HIP_MEMORY_SCOPE_AGENT) < rtarget)
            __builtin_amdgcn_s_sleep(2);
    }
    __syncthreads();
}

__global__ __launch_bounds__(768, 1) void gru_scan_fb(
    const float* __restrict__ a, const float* __restrict__ h0,
    const float* __restrict__ Wih, const float* __restrict__ Whh,
    const float* __restrict__ bias, const float* __restrict__ bias_n,
    const float* __restrict__ Wout, const float* __restrict__ bout,
    float* __restrict__ out, u64* __restrict__ hbufA, u64* __restrict__ hbufB,
    u32* __restrict__ leaf, u32* __restrict__ root)
{
    __shared__ float sWhh[12][WW];
    __shared__ __align__(16) u64 sh[8192];
    __shared__ float sPreH[2][12][32];
    __shared__ float sIg[2][2][12][32];
    __shared__ float sOutPart[12][64];

    const int g   = blockIdx.x;
    const int tid = threadIdx.x;
    const int w0  = g * 4;

    for (int i = tid; i < 12 * (WW / 4); i += 768) {
        int row_ = i / (WW / 4);
        int k4_  = i - row_ * (WW / 4);
        int gr   = (row_ >> 2) * WW + w0 + (row_ & 3);
        *(float4*)&sWhh[row_][k4_ * 4] = *(const float4*)&Whh[(size_t)gr * WW + k4_ * 4];
    }
    const int  half = (tid >= 384) ? 1 : 0;
    const int  sub  = tid - half * 384;
    const int  b1   = sub & 31;
    const int  row  = sub >> 5;
    const int  grow = (row >> 2) * WW + w0 + (row & 3);
    const float biasv = (half == 0) ? bias[grow] : 0.0f;

    float ho0 = 0.f, ho1 = 0.f, ho2 = 0.f, ho3 = 0.f;
    float bn0 = 0.f, bn1 = 0.f, bn2 = 0.f, bn3 = 0.f;
    if (tid < 32) {
        ho0 = h0[w0 + 0]; ho1 = h0[w0 + 1]; ho2 = h0[w0 + 2]; ho3 = h0[w0 + 3];
        bn0 = bias_n[w0 + 0]; bn1 = bias_n[w0 + 1]; bn2 = bias_n[w0 + 2]; bn3 = bias_n[w0 + 3];
        u32 lo = bfround(ho0) | (bfround(ho1) << 16);
        u32 hi = bfround(ho2) | (bfround(ho3) << 16);
        STA64(&hbufA[g * 32 + tid], (u64)lo | ((u64)hi << 32));
    }
    const int  p0  = (g & 31) * 16;
    const int  b0  = (g >> 5) * 4;
    const int  o   = tid & 63;
    const int  c   = tid >> 6;
    const int  p3p = p0 + (o & 15);
    const int  p3b = b0 + (o >> 4);
    const float boutv = bout[p3p];

    auto ihdot = [&](int t_, int pbuf) {
        const float4* __restrict__ arow = (const float4*)&a[((size_t)b1 * TT + t_) * PP];
        const float4* __restrict__ wrow = (const float4*)&Wih[(size_t)grow * PP];
        const int p40 = half * 64;
        float4 acc = {0.f, 0.f, 0.f, 0.f};
        #pragma unroll 8
        for (int p4 = 0; p4 < 64; ++p4) {
            float4 av = arow[p40 + p4];
            float4 wv = wrow[p40 + p4];
            acc.x += av.x * wv.x; acc.y += av.y * wv.y;
            acc.z += av.z * wv.z; acc.w += av.w * wv.w;
        }
        sIg[pbuf][half][row][b1] = (acc.x + acc.y) + (acc.z + acc.w) + biasv;
    };
    auto p3partials = [&]() {
        const float4* __restrict__ wrow = (const float4*)&Wout[(size_t)p3p * WW];
        float4 acc = {0.f, 0.f, 0.f, 0.f};
        for (int k4 = c; k4 < WW / 4; k4 += 12) {
            u64 pk = sh[k4 * 32 + p3b];
            float4 wv = wrow[k4];
            acc.x += bflo((u32)pk) * wv.x;
            acc.y += bfhi((u32)pk) * wv.y;
            acc.z += bflo((u32)(pk >> 32)) * wv.z;
            acc.w += bfhi((u32)(pk >> 32)) * wv.w;
        }
        sOutPart[c][o] = (acc.x + acc.y) + (acc.z + acc.w);
    };

    ihdot(TT - 1, 1);
    u32 rtarget = 8;
    grid_barrier32(leaf, root, rtarget, g);
    u64* hcur = hbufA;
    u64* hnxt = hbufB;

    for (int t = TT - 1; t >= 0; --t) {
        const int par = t & 1;
        u64 r0, r1, r2, r3, r4, r5, r6, r7, r8, r9, r10 = 0;
        #define LDH(J) LDA64(&hcur[tid + (J) * 768])
        r0 = LDH(0); r1 = LDH(1); r2 = LDH(2); r3 = LDH(3); r4 = LDH(4);
        r5 = LDH(5); r6 = LDH(6); r7 = LDH(7); r8 = LDH(8); r9 = LDH(9);
        if (tid < 512) r10 = LDH(10);
        #undef LDH
        if (t > 0) ihdot(t - 1, par ^ 1);
        sh[tid] = r0;          sh[tid + 768] = r1;   sh[tid + 1536] = r2;
        sh[tid + 2304] = r3;   sh[tid + 3072] = r4;  sh[tid + 3840] = r5;
        sh[tid + 4608] = r6;   sh[tid + 5376] = r7;  sh[tid + 6144] = r8;
        sh[tid + 6912] = r9;
        if (tid < 512) sh[tid + 7680] = r10;
        __syncthreads();
        {
            const int k40 = half * 128;
            float4 acc = {0.f, 0.f, 0.f, 0.f};
            #pragma unroll 4
            for (int k4 = 0; k4 < 128; ++k4) {
                u64 pk = sh[(k40 + k4) * 32 + b1];
                float4 wv = *(const float4*)&sWhh[row][(k40 + k4) * 4];
                acc.x += bflo((u32)pk) * wv.x;
                acc.y += bfhi((u32)pk) * wv.y;
                acc.z += bflo((u32)(pk >> 32)) * wv.z;
                acc.w += bfhi((u32)(pk >> 32)) * wv.w;
            }
            sPreH[half][row][b1] = (acc.x + acc.y) + (acc.z + acc.w);
        }
        if (t < TT - 1) p3partials();
        __syncthreads();
        if (tid < 32) {
            const int b = tid;
            float hn0, hn1, hn2, hn3;
            {
                float rr = 1.f / (1.f + __expf(-(sIg[par][0][0][b] + sIg[par][1][0][b] + sPreH[0][0][b] + sPreH[1][0][b])));
                float zz = 1.f / (1.f + __expf(-(sIg[par][0][4][b] + sIg[par][1][4][b] + sPreH[0][4][b] + sPreH[1][4][b])));
                float nn = tanhf(sIg[par][0][8][b] + sIg[par][1][8][b] + rr * (sPreH[0][8][b] + sPreH[1][8][b] + bn0));
                hn0 = nn + zz * (ho0 - nn); ho0 = hn0;
            }
            {
                float rr = 1.f / (1.f + __expf(-(sIg[par][0][1][b] + sIg[par][1][1][b] + sPreH[0][1][b] + sPreH[1][1][b])));
                float zz = 1.f / (1.f + __expf(-(sIg[par][0][5][b] + sIg[par][1][5][b] + sPreH[0][5][b] + sPreH[1][5][b])));
                float nn = tanhf(sIg[par][0][9][b] + sIg[par][1][9][b] + rr * (sPreH[0][9][b] + sPreH[1][9][b] + bn1));
                hn1 = nn + zz * (ho1 - nn); ho1 = hn1;
            }
            {
                float rr = 1.f / (1.f + __expf(-(sIg[par][0][2][b] + sIg[par][1][2][b] + sPreH[0][2][b] + sPreH[1][2][b])));
                float zz = 1.f / (1.f + __expf(-(sIg[par][0][6][b] + sIg[par][1][6][b] + sPreH[0][6][b] + sPreH[1][6][b])));
                float nn = tanhf(sIg[par][0][10][b] + sIg[par][1][10][b] + rr * (sPreH[0][10][b] + sPreH[1][10][b] + bn2));
                hn2 = nn + zz * (ho2 - nn); ho2 = hn2;
            }
            {
                float rr = 1.f / (1.f + __expf(-(sIg[par][0][3][b] + sIg[par][1][3][b] + sPreH[0][3][b] + sPreH[1][3][b])));
                float zz = 1.f / (1.f + __expf(-(sIg[par][0][7][b] + sIg[par][1][7][b] + sPreH[0][7][b] + sPreH[1][7][b])));
                float nn = tanhf(sIg[par][0][11][b] + sIg[par][1][11][b] + rr * (sPreH[0][11][b] + sPreH[1][11][b] + bn3));
                hn3 = nn + zz * (ho3 - nn); ho3 = hn3;
            }
            u32 lo = bfround(hn0) | (bfround(hn1) << 16);
            u32 hi = bfround(hn2) | (bfround(hn3) << 16);
            STA64(&hnxt[g * 32 + tid], (u64)lo | ((u64)hi << 32));
        }
        if (t < TT - 1 && tid < 64) {
            float s_ = boutv;
            #pragma unroll
            for (int cc = 0; cc < 12; ++cc) s_ += sOutPart[cc][o];
            out[((size_t)p3b * TT + (t + 1)) * PP + p3p] = s_;
        }
        rtarget += 8;
        grid_barrier32(leaf, root, rtarget, g);
        u64* tmp = hcur; hcur = hnxt; hnxt = tmp;
    }
    {
        u64 r0, r1, r2, r3, r4, r5, r6, r7, r8, r9, r10 = 0;
        #define LDH(J) LDA64(&hcur[tid + (J) * 768])
        r0 = LDH(0); r1 = LDH(1); r2 = LDH(2); r3 = LDH(3); r4 = LDH(4);
        r5 = LDH(5); r6 = LDH(6); r7 = LDH(7); r8 = LDH(8); r9 = LDH(9);
        if (tid < 512) r10 = LDH(10);
        #undef LDH
        sh[tid] = r0;          sh[tid + 768] = r1;   sh[tid + 1536] = r2;
        sh[tid + 2304] = r3;   sh[tid + 3072] = r4;  sh[tid + 3840] = r5;
        sh[tid + 4608] = r6;   sh[tid + 5376] = r7;  sh[tid + 6144] = r8;
        sh[tid + 6912] = r9;
        if (tid < 512) sh[tid + 7680] = r10;
        __syncthreads();
        p3partials();
        __syncthreads();
        if (tid < 64) {
            float s_ = boutv;
            #pragma unroll
            for (int cc = 0; cc < 12; ++cc) s_ += sOutPart[cc][o];
            out[((size_t)p3b * TT) * PP + p3p] = s_;
        }
    }
}

extern "C" void kernel_launch(void* const* d_in, const int* in_sizes, int n_in,
                              void* d_out, int out_size, void* d_ws, size_t ws_size,
                              hipStream_t stream) {
    const float* a      = (const float*)d_in[0];
    const float* h0     = (const float*)d_in[1];
    const float* Wih    = (const float*)d_in[2];
    const float* Whh    = (const float*)d_in[3];
    const float* bias   = (const float*)d_in[4];
    const float* bias_n = (const float*)d_in[5];
    const float* Wout   = (const float*)d_in[6];
    const float* bout   = (const float*)d_in[7];
    float* out = (float*)d_out;

    const size_t IG_BYTES   = (size_t)TT * 64 * 3072;       // 805,306,368
    const size_t ABF2_BYTES = (size_t)TT * 64 * 32 * 8 * 2; // 134,217,728
    const size_t BUF_BYTES  = 32768;                        // per chain per parity
    const size_t NEED_FULL  = IG_BYTES + ABF2_BYTES + 4 * BUF_BYTES + 8192;
    const size_t NEED_MID   = IG_BYTES + 4 * BUF_BYTES + 8192;

    if (ws_size >= NEED_FULL) {
        char* igbase = (char*)d_ws;
        u16*  abf2   = (u16*)((char*)d_ws + IG_BYTES);
        char* bufs   = (char*)d_ws + IG_BYTES + ABF2_BYTES;
        u64*  bufA0  = (u64*)(bufs);
        u64*  bufA1  = (u64*)(bufs + BUF_BYTES);
        u64*  bufB0  = (u64*)(bufs + 2 * BUF_BYTES);
        u64*  bufB1  = (u64*)(bufs + 3 * BUF_BYTES);
        u32*  flagsA = (u32*)(bufs + 4 * BUF_BYTES);
        u32*  flagsB = flagsA + 1024;
        hipMemsetAsync(flagsA, 0, 8192, stream);
        hipLaunchKernelGGL(a2bf_t, dim3(TT), dim3(256), 0, stream, a, abf2);
        hipLaunchKernelGGL(ig_prepass10, dim3(64, 32), dim3(768), 0, stream,
                           abf2, Wih, bias, igbase);
        void* args[] = {(void*)&h0, (void*)&Whh, (void*)&bias_n, (void*)&Wout,
                        (void*)&bout, (void*)&igbase, (void*)&out,
                        (void*)&bufA0, (void*)&bufA1, (void*)&bufB0, (void*)&bufB1,
                        (void*)&flagsA, (void*)&flagsB};
        hipLaunchCooperativeKernel((void*)gru_scan7, dim3(64), dim3(768),
                                   args, 0, stream);
    } else if (ws_size >= NEED_MID) {
        char* igbase = (char*)d_ws;
        char* bufs   = (char*)d_ws + IG_BYTES;
        u64*  bufA0  = (u64*)(bufs);
        u64*  bufA1  = (u64*)(bufs + BUF_BYTES);
        u64*  bufB0  = (u64*)(bufs + 2 * BUF_BYTES);
        u64*  bufB1  = (u64*)(bufs + 3 * BUF_BYTES);
        u32*  flagsA = (u32*)(bufs + 4 * BUF_BYTES);
        u32*  flagsB = flagsA + 1024;
        hipMemsetAsync(flagsA, 0, 8192, stream);
        hipLaunchKernelGGL(ig_prepass16, dim3(16, 64), dim3(768), 0, stream,
                           a, Wih, bias, igbase);
        void* args[] = {(void*)&h0, (void*)&Whh, (void*)&bias_n, (void*)&Wout,
                        (void*)&bout, (void*)&igbase, (void*)&out,
                        (void*)&bufA0, (void*)&bufA1, (void*)&bufB0, (void*)&bufB1,
                        (void*)&flagsA, (void*)&flagsB};
        hipLaunchCooperativeKernel((void*)gru_scan7, dim3(64), dim3(768),
                                   args, 0, stream);
    } else {
        u64* hA   = (u64*)d_ws;
        u64* hB   = hA + 8192;
        u32* leaf = (u32*)((char*)d_ws + 2 * 65536);
        u32* root = leaf + 8 * 16;
        hipMemsetAsync(leaf, 0, 1024, stream);
        void* args[] = {(void*)&a, (void*)&h0, (void*)&Wih, (void*)&Whh,
                        (void*)&bias, (void*)&bias_n, (void*)&Wout, (void*)&bout,
                        (void*)&out, (void*)&hA, (void*)&hB, (void*)&leaf, (void*)&root};
        hipLaunchCooperativeKernel((void*)gru_scan_fb, dim3(256), dim3(768),
                                   args, 0, stream);
    }
}

// Round 14
// 17042.444 us; speedup vs baseline: 1.7086x; 1.7086x over previous
//
#include <hip/hip_runtime.h>
#include <cstddef>

#define TT 4096
#define PP 512
#define WW 1024

using u32 = unsigned;
using u64 = unsigned long long;
using u16 = unsigned short;

typedef short short8 __attribute__((ext_vector_type(8)));
typedef float f32x4 __attribute__((ext_vector_type(4)));

__device__ __forceinline__ u32 bfround(float f) {
    u32 u = __float_as_uint(f);
    return (u + 0x7fffu + ((u >> 16) & 1u)) >> 16;
}
__device__ __forceinline__ float bf2f(u32 q) { return __uint_as_float(q << 16); }
__device__ __forceinline__ float bflo(u32 q) { return __uint_as_float(q << 16); }
__device__ __forceinline__ float bfhi(u32 q) { return __uint_as_float(q & 0xffff0000u); }

#define LDA64(p)    __hip_atomic_load((p),  __ATOMIC_RELAXED, __HIP_MEMORY_SCOPE_AGENT)
#define STA64(p, v) __hip_atomic_store((p), (v), __ATOMIC_RELAXED, __HIP_MEMORY_SCOPE_AGENT)
#define LDA32(p)    __hip_atomic_load((p),  __ATOMIC_RELAXED, __HIP_MEMORY_SCOPE_AGENT)
#define STA32(p, v) __hip_atomic_store((p), (v), __ATOMIC_RELAXED, __HIP_MEMORY_SCOPE_AGENT)
#define STA16(p, v) __hip_atomic_store((p), (v), __ATOMIC_RELAXED, __HIP_MEMORY_SCOPE_AGENT)

// ===================== FUSED: scan4 role (WGs 0-63) + prepass role (WGs 64-255) =====================
// ig layout: u16[((t*64 + gWG)*32 + b)*48 + slot], slot = gate*16 + (w&15)
// Prepass j-block owns w in [j*128,(j+1)*128) x 3 gates -> assembles 8 full gWG tiles
// in LDS, burst-stores 24KB contiguous (full lines, agent scope). Chunk flag per 64-t.
union SMemF {
    struct {                                  // scan role (33.8 KB)
        float sPreH[4][48][2][17];
        float sOutP[4][16][18];
        u64   sIgRaw[384];
    } s;
    struct {                                  // prepass role (57.3 KB)
        u16 aLds[32][520];
        u16 sIgT[8][32][48];
    } p;
};

__global__ __launch_bounds__(768, 1) void gru_fused2(
    const float* __restrict__ a, const float* __restrict__ h0v,
    const float* __restrict__ Wih, const float* __restrict__ Whh,
    const float* __restrict__ bias, const float* __restrict__ bias_n,
    const float* __restrict__ Wout, const float* __restrict__ bout,
    char* __restrict__ igbase, float* __restrict__ out,
    u64* __restrict__ bufA, u64* __restrict__ bufB,
    u32* __restrict__ flags, u32* __restrict__ igready)
{
    __shared__ __align__(16) SMemF sm;

    const int bid  = blockIdx.x;
    const int tid  = threadIdx.x;
    const int lane = tid & 63;
    const int wid  = tid >> 6;
    const int lq   = lane >> 4;
    const int bcol = lane & 15;

    if (bid < 64) {
        // ======================= SCAN ROLE (scan4 verbatim + chunk gate) =======================
        const int g   = bid;
        const int p0  = (g >> 1) * 16;
        const int pb0 = (g & 1) * 16;

        short8 frag[24];
        if (wid < 8) {
            const int kq = wid & 3;
            #pragma unroll
            for (int gate = 0; gate < 3; ++gate)
                #pragma unroll
                for (int s = 0; s < 8; ++s) {
                    const float* wr = &Whh[(size_t)(gate * WW + g * 16 + bcol) * WW
                                           + (kq * 8 + s) * 32 + lq * 8];
                    float t8[8];
                    *(float4*)&t8[0] = *(const float4*)&wr[0];
                    *(float4*)&t8[4] = *(const float4*)&wr[4];
                    short8 v;
                    #pragma unroll
                    for (int j = 0; j < 8; ++j) v[j] = (short)bfround(t8[j]);
                    frag[gate * 8 + s] = v;
                }
        } else {
            const int kq3 = wid - 8;
            #pragma unroll
            for (int s = 0; s < 8; ++s) {
                const float* wr = &Wout[(size_t)(p0 + bcol) * WW + (kq3 * 8 + s) * 32 + lq * 8];
                float t8[8];
                *(float4*)&t8[0] = *(const float4*)&wr[0];
                *(float4*)&t8[4] = *(const float4*)&wr[4];
                short8 v;
                #pragma unroll
                for (int j = 0; j < 8; ++j) v[j] = (short)bfround(t8[j]);
                frag[s] = v;
            }
        }

        float h_own = 0.f, bnv = 0.f;
        int gwl = 0, gb = 0; u32 hidx16 = 0;
        if (tid >= 256) {
            const int idx = tid - 256;
            gwl = idx & 15; gb = idx >> 4;
            h_own = h0v[g * 16 + gwl];
            bnv   = bias_n[g * 16 + gwl];
            const int w_abs = g * 16 + gwl;
            const int ip = (w_abs >> 3) * 64 + 2 * gb + ((w_abs >> 2) & 1);
            hidx16 = 4 * ip + (w_abs & 3);
            STA16(&((u16*)bufA)[hidx16], (u16)bfround(h_own));
        }
        const float boutp = (tid < 256) ? bout[p0 + (tid & 15)] : 0.f;

        const int fo_hh = lq * 32 + ((wid >> 2) & 1) * 16 + bcol;
        const int fo_p3 = lq * 32 + pb0 + bcol;

        u64* hcur = bufA;
        u64* hnxt = bufB;
        u32 kk = 1;

        for (int t = TT - 1; t >= 0; --t) {
            if (t < TT - 2 && tid < 256) {
                const int p = tid & 15, b = tid >> 4;
                float s_ = boutp;
                #pragma unroll
                for (int cc = 0; cc < 4; ++cc) s_ += sm.s.sOutP[cc][p][b];
                out[((size_t)(pb0 + b) * TT + (t + 2)) * PP + p0 + p] = s_;
            }
            if (wid >= 4) asm volatile("s_waitcnt vmcnt(0)" ::: "memory");
            __syncthreads();
            if (tid == 0) STA32(&flags[g * 16], kk);

            // chunk gate (once per 64 steps; loaders only, divergent-safe)
            if ((t & 63) == 63 && tid < 384) {
                while (LDA32(&igready[(t >> 6) * 16]) < 8u)
                    __builtin_amdgcn_s_sleep(8);
            }
            u64 igr = 0;
            if (tid < 384) igr = *(const u64*)(igbase + ((size_t)t * 64 + g) * 3072 + tid * 8);

            for (;;) {
                u32 v = LDA32(&flags[lane * 16]);
                if (__all((int)(v - kk) >= 0)) break;
                __builtin_amdgcn_s_sleep(1);
            }
            asm volatile("" ::: "memory");

            if (wid < 8) {
                const int kq = wid & 3;
                f32x4 c0 = {0.f,0.f,0.f,0.f}, c1 = {0.f,0.f,0.f,0.f}, c2 = {0.f,0.f,0.f,0.f};
                #pragma unroll
                for (int s = 0; s < 8; ++s) {
                    const int ss = kq * 8 + s;
                    const u64 q0 = LDA64(&hcur[2 * (ss * 128 + fo_hh)]);
                    const u64 q1 = LDA64(&hcur[2 * (ss * 128 + fo_hh) + 1]);
                    union { u64 q[2]; short8 v; } uu; uu.q[0] = q0; uu.q[1] = q1;
                    c0 = __builtin_amdgcn_mfma_f32_16x16x32_bf16(frag[s],      uu.v, c0, 0, 0, 0);
                    c1 = __builtin_amdgcn_mfma_f32_16x16x32_bf16(frag[8 + s],  uu.v, c1, 0, 0, 0);
                    c2 = __builtin_amdgcn_mfma_f32_16x16x32_bf16(frag[16 + s], uu.v, c2, 0, 0, 0);
                }
                const int bt = wid >> 2, r0 = lq * 4;
                #pragma unroll
                for (int r = 0; r < 4; ++r) {
                    sm.s.sPreH[kq][r0 + r][bt][bcol]      = c0[r];
                    sm.s.sPreH[kq][16 + r0 + r][bt][bcol] = c1[r];
                    sm.s.sPreH[kq][32 + r0 + r][bt][bcol] = c2[r];
                }
            } else {
                const int kq3 = wid - 8;
                f32x4 d = {0.f, 0.f, 0.f, 0.f};
                #pragma unroll
                for (int s = 0; s < 8; ++s) {
                    const int ss = kq3 * 8 + s;
                    const u64 q0 = LDA64(&hcur[2 * (ss * 128 + fo_p3)]);
                    const u64 q1 = LDA64(&hcur[2 * (ss * 128 + fo_p3) + 1]);
                    union { u64 q[2]; short8 v; } uu; uu.q[0] = q0; uu.q[1] = q1;
                    d = __builtin_amdgcn_mfma_f32_16x16x32_bf16(frag[s], uu.v, d, 0, 0, 0);
                }
                const int r0 = lq * 4;
                #pragma unroll
                for (int r = 0; r < 4; ++r) sm.s.sOutP[kq3][r0 + r][bcol] = d[r];
            }
            if (tid < 384) sm.s.sIgRaw[tid] = igr;
            __syncthreads();

            if (tid >= 256) {
                const u16* sIgU = (const u16*)sm.s.sIgRaw;
                const float ig_r = bf2f(sIgU[gb * 48 + gwl]);
                const float ig_z = bf2f(sIgU[gb * 48 + 16 + gwl]);
                const float ig_n = bf2f(sIgU[gb * 48 + 32 + gwl]);
                const int bh = gb >> 4, bc = gb & 15;
                const float hg_r = sm.s.sPreH[0][gwl][bh][bc] + sm.s.sPreH[1][gwl][bh][bc]
                                 + sm.s.sPreH[2][gwl][bh][bc] + sm.s.sPreH[3][gwl][bh][bc];
                const float hg_z = sm.s.sPreH[0][16 + gwl][bh][bc] + sm.s.sPreH[1][16 + gwl][bh][bc]
                                 + sm.s.sPreH[2][16 + gwl][bh][bc] + sm.s.sPreH[3][16 + gwl][bh][bc];
                const float hg_n = sm.s.sPreH[0][32 + gwl][bh][bc] + sm.s.sPreH[1][32 + gwl][bh][bc]
                                 + sm.s.sPreH[2][32 + gwl][bh][bc] + sm.s.sPreH[3][32 + gwl][bh][bc];
                const float rr = __builtin_amdgcn_rcpf(1.f + __expf(-(ig_r + hg_r)));
                const float zz = __builtin_amdgcn_rcpf(1.f + __expf(-(ig_z + hg_z)));
                const float xn = ig_n + rr * (hg_n + bnv);
                const float nn = 2.f * __builtin_amdgcn_rcpf(1.f + __expf(-2.f * xn)) - 1.f;
                h_own = nn + zz * (h_own - nn);
                STA16(&((u16*)hnxt)[hidx16], (u16)bfround(h_own));
            }

            u64* tmp = hcur; hcur = hnxt; hnxt = tmp;
            ++kk;
        }

        // epilogue: out[1] from t=0 iteration's sOutP, then s_0 -> out[:,0,:]
        if (tid < 256) {
            const int p = tid & 15, b = tid >> 4;
            float s_ = boutp;
            #pragma unroll
            for (int cc = 0; cc < 4; ++cc) s_ += sm.s.sOutP[cc][p][b];
            out[((size_t)(pb0 + b) * TT + 1) * PP + p0 + p] = s_;
        }
        if (wid >= 4) asm volatile("s_waitcnt vmcnt(0)" ::: "memory");
        __syncthreads();
        if (tid == 0) STA32(&flags[g * 16], kk);
        if (wid >= 8) {
            for (;;) {
                u32 v = LDA32(&flags[lane * 16]);
                if (__all((int)(v - kk) >= 0)) break;
                __builtin_amdgcn_s_sleep(1);
            }
            asm volatile("" ::: "memory");
            const int kq3 = wid - 8;
            f32x4 d = {0.f, 0.f, 0.f, 0.f};
            #pragma unroll
            for (int s = 0; s < 8; ++s) {
                const int ss = kq3 * 8 + s;
                const u64 q0 = LDA64(&hcur[2 * (ss * 128 + fo_p3)]);
                const u64 q1 = LDA64(&hcur[2 * (ss * 128 + fo_p3) + 1]);
                union { u64 q[2]; short8 v; } uu; uu.q[0] = q0; uu.q[1] = q1;
                d = __builtin_amdgcn_mfma_f32_16x16x32_bf16(frag[s], uu.v, d, 0, 0, 0);
            }
            const int r0 = lq * 4;
            #pragma unroll
            for (int r = 0; r < 4; ++r) sm.s.sOutP[kq3][r0 + r][bcol] = d[r];
        }
        __syncthreads();
        if (tid < 256) {
            const int p = tid & 15, b = tid >> 4;
            const float s_ = boutp + sm.s.sOutP[0][p][b] + sm.s.sOutP[1][p][b]
                                   + sm.s.sOutP[2][p][b] + sm.s.sOutP[3][p][b];
            out[((size_t)(pb0 + b) * TT) * PP + p0 + p] = s_;
        }
    } else {
        // ======================= PREPASS ROLE =======================
        const int pid = bid - 64;                 // 0..191
        for (int vb = pid; vb < 512; vb += 192) {
            const int j  = vb & 7;
            const int tb = 63 - (vb >> 3);        // reverse-t chunks first

            // Wih fragments: 2 tiles per wave, tile ti = wid*2+rt -> (gate, gl)
            short8 af[2][16];
            float  bi[2][4];
            #pragma unroll
            for (int rt = 0; rt < 2; ++rt) {
                const int ti = wid * 2 + rt;
                const int gate_t = ti >> 3, gl_t = ti & 7;
                const int rowb = gate_t * WW + j * 128 + gl_t * 16;
                const float* wr = &Wih[(size_t)(rowb + bcol) * PP + lq * 8];
                #pragma unroll
                for (int s = 0; s < 16; ++s) {
                    float t8[8];
                    *(float4*)&t8[0] = *(const float4*)&wr[s * 32];
                    *(float4*)&t8[4] = *(const float4*)&wr[s * 32 + 4];
                    #pragma unroll
                    for (int jj = 0; jj < 8; ++jj) af[rt][s][jj] = (short)bfround(t8[jj]);
                }
                #pragma unroll
                for (int r = 0; r < 4; ++r) bi[rt][r] = bias[rowb + lq * 4 + r];
            }

            for (int tt = 0; tt < 64; ++tt) {
                const int t = tb * 64 + tt;
                // stage a_t (full 32 batches) -> LDS bf16
                for (int i = tid; i < 2048; i += 768) {
                    const int b = i >> 6, oct = i & 63;
                    const float* ap = &a[((size_t)b * TT + t) * PP + oct * 8];
                    float4 f0 = *(const float4*)&ap[0];
                    float4 f1 = *(const float4*)&ap[4];
                    uint2 w0, w1;
                    w0.x = bfround(f0.x) | (bfround(f0.y) << 16);
                    w0.y = bfround(f0.z) | (bfround(f0.w) << 16);
                    w1.x = bfround(f1.x) | (bfround(f1.y) << 16);
                    w1.y = bfround(f1.z) | (bfround(f1.w) << 16);
                    *(uint2*)&sm.p.aLds[b][oct * 8]     = w0;
                    *(uint2*)&sm.p.aLds[b][oct * 8 + 4] = w1;
                }
                __syncthreads();
                // MFMA: 2 tiles x 2 b-halves x 16 kslices; stage into sIgT
                #pragma unroll
                for (int rt = 0; rt < 2; ++rt) {
                    const int ti = wid * 2 + rt;
                    const int gate_t = ti >> 3, gl_t = ti & 7;
                    #pragma unroll
                    for (int bh = 0; bh < 2; ++bh) {
                        f32x4 d = {0.f, 0.f, 0.f, 0.f};
                        #pragma unroll 4
                        for (int s = 0; s < 16; ++s) {
                            short8 bf = *(const short8*)&sm.p.aLds[bh * 16 + bcol][s * 32 + lq * 8];
                            d = __builtin_amdgcn_mfma_f32_16x16x32_bf16(af[rt][s], bf, d, 0, 0, 0);
                        }
                        u32 lo = bfround(d[0] + bi[rt][0]) | (bfround(d[1] + bi[rt][1]) << 16);
                        u32 hi = bfround(d[2] + bi[rt][2]) | (bfround(d[3] + bi[rt][3]) << 16);
                        *(u64*)&sm.p.sIgT[gl_t][bh * 16 + bcol][gate_t * 16 + lq * 4] =
                            (u64)lo | ((u64)hi << 32);
                    }
                }
                __syncthreads();
                // burst store: 8 full tiles = 3072 u64 contiguous (gWG j*8..j*8+7)
                {
                    const u64* src = (const u64*)sm.p.sIgT;
                    u64* dst = (u64*)(igbase + ((size_t)t * 64 + j * 8) * 3072);
                    #pragma unroll
                    for (int r = 0; r < 4; ++r) STA64(&dst[r * 768 + tid], src[r * 768 + tid]);
                }
                __syncthreads();
            }
            // chunk contribution complete: drain, then signal
            asm volatile("s_waitcnt vmcnt(0)" ::: "memory");
            __syncthreads();
            if (tid == 0)
                __hip_atomic_fetch_add(&igready[tb * 16], 1u,
                                       __ATOMIC_RELAXED, __HIP_MEMORY_SCOPE_AGENT);
        }
    }
}

// ============ PREPASS v2 (mid-tier, f32 a, proven) ============
__global__ __launch_bounds__(768, 1) void ig_prepass16(
    const float* __restrict__ a, const float* __restrict__ Wih,
    const float* __restrict__ bias, char* __restrict__ igbase)
{
    const int gp   = blockIdx.x;
    const int t0   = blockIdx.y * 64;
    const int tid  = threadIdx.x;
    const int lane = tid & 63;
    const int wid  = tid >> 6;
    const int growb = gp * 192 + wid * 16;

    short8 afrag[16];
    float  biasv[4];
    {
        const float* wr = &Wih[(size_t)(growb + (lane & 15)) * PP + (lane >> 4) * 8];
        #pragma unroll
        for (int s = 0; s < 16; ++s) {
            float t8[8];
            *(float4*)&t8[0] = *(const float4*)&wr[s * 32];
            *(float4*)&t8[4] = *(const float4*)&wr[s * 32 + 4];
            #pragma unroll
            for (int j = 0; j < 8; ++j) afrag[s][j] = (short)bfround(t8[j]);
        }
        #pragma unroll
        for (int r = 0; r < 4; ++r) biasv[r] = bias[growb + (lane >> 4) * 4 + r];
    }
    const int grow0 = growb + (lane >> 4) * 4;
    const int gate  = grow0 >> 10;
    const int w     = grow0 & 1023;
    const int gWG   = w >> 4;
    const int slot  = gate * 16 + (w & 15);
    const int bcol  = lane & 15;

    for (int ct = 0; ct < 128; ++ct) {
        const int t = t0 + (ct >> 1);
        const int b = (ct & 1) * 16 + bcol;
        const float* ap = &a[((size_t)b * TT + t) * PP + (lane >> 4) * 8];
        f32x4 d = {0.f, 0.f, 0.f, 0.f};
        #pragma unroll 4
        for (int s = 0; s < 16; ++s) {
            float4 lo = *(const float4*)&ap[s * 32];
            float4 hi = *(const float4*)&ap[s * 32 + 4];
            short8 bfv;
            bfv[0] = (short)((__float_as_uint(lo.x) + 0x8000u) >> 16);
            bfv[1] = (short)((__float_as_uint(lo.y) + 0x8000u) >> 16);
            bfv[2] = (short)((__float_as_uint(lo.z) + 0x8000u) >> 16);
            bfv[3] = (short)((__float_as_uint(lo.w) + 0x8000u) >> 16);
            bfv[4] = (short)((__float_as_uint(hi.x) + 0x8000u) >> 16);
            bfv[5] = (short)((__float_as_uint(hi.y) + 0x8000u) >> 16);
            bfv[6] = (short)((__float_as_uint(hi.z) + 0x8000u) >> 16);
            bfv[7] = (short)((__float_as_uint(hi.w) + 0x8000u) >> 16);
            d = __builtin_amdgcn_mfma_f32_16x16x32_bf16(afrag[s], bfv, d, 0, 0, 0);
        }
        u32 lo32 = bfround(d[0] + biasv[0]) | (bfround(d[1] + biasv[1]) << 16);
        u32 hi32 = bfround(d[2] + biasv[2]) | (bfround(d[3] + biasv[3]) << 16);
        *(u64*)(igbase + (((size_t)t * 64 + gWG) * 1536 + (size_t)b * 48 + slot) * 2) =
            (u64)lo32 | ((u64)hi32 << 32);
    }
}

// ============ SCAN v4 standalone (mid-tier, proven 15.3 ms) ============
__global__ __launch_bounds__(768, 1) void gru_scan4(
    const float* __restrict__ h0v, const float* __restrict__ Whh,
    const float* __restrict__ bias_n, const float* __restrict__ Wout,
    const float* __restrict__ bout, const char* __restrict__ igbase,
    float* __restrict__ out, u64* __restrict__ bufA, u64* __restrict__ bufB,
    u32* __restrict__ flags)
{
    __shared__ float sPreH[4][48][2][17];
    __shared__ float sOutP[4][16][18];
    __shared__ __align__(8) u64 sIgRaw[384];

    const int g    = blockIdx.x;
    const int tid  = threadIdx.x;
    const int lane = tid & 63;
    const int wid  = tid >> 6;
    const int p0   = (g >> 1) * 16;
    const int pb0  = (g & 1) * 16;

    short8 frag[24];
    if (wid < 8) {
        const int kq = wid & 3;
        #pragma unroll
        for (int gate = 0; gate < 3; ++gate)
            #pragma unroll
            for (int s = 0; s < 8; ++s) {
                const float* wr = &Whh[(size_t)(gate * WW + g * 16 + (lane & 15)) * WW
                                       + (kq * 8 + s) * 32 + (lane >> 4) * 8];
                float t8[8];
                *(float4*)&t8[0] = *(const float4*)&wr[0];
                *(float4*)&t8[4] = *(const float4*)&wr[4];
                short8 v;
                #pragma unroll
                for (int j = 0; j < 8; ++j) v[j] = (short)bfround(t8[j]);
                frag[gate * 8 + s] = v;
            }
    } else {
        const int kq3 = wid - 8;
        #pragma unroll
        for (int s = 0; s < 8; ++s) {
            const float* wr = &Wout[(size_t)(p0 + (lane & 15)) * WW
                                    + (kq3 * 8 + s) * 32 + (lane >> 4) * 8];
            float t8[8];
            *(float4*)&t8[0] = *(const float4*)&wr[0];
            *(float4*)&t8[4] = *(const float4*)&wr[4];
            short8 v;
            #pragma unroll
            for (int j = 0; j < 8; ++j) v[j] = (short)bfround(t8[j]);
            frag[s] = v;
        }
    }

    float h_own = 0.f, bnv = 0.f;
    int gwl = 0, gb = 0; u32 hidx16 = 0;
    if (tid >= 256) {
        const int idx = tid - 256;
        gwl = idx & 15; gb = idx >> 4;
        h_own = h0v[g * 16 + gwl];
        bnv   = bias_n[g * 16 + gwl];
        const int w_abs = g * 16 + gwl;
        const int ip = (w_abs >> 3) * 64 + 2 * gb + ((w_abs >> 2) & 1);
        hidx16 = 4 * ip + (w_abs & 3);
        STA16(&((u16*)bufA)[hidx16], (u16)bfround(h_own));
    }
    const float boutp = (tid < 256) ? bout[p0 + (tid & 15)] : 0.f;

    const int fo_hh = (lane >> 4) * 32 + ((wid >> 2) & 1) * 16 + (lane & 15);
    const int fo_p3 = (lane >> 4) * 32 + pb0 + (lane & 15);

    u64* hcur = bufA;
    u64* hnxt = bufB;
    u32 kk = 1;

    for (int t = TT - 1; t >= 0; --t) {
        if (t < TT - 2 && tid < 256) {
            const int p = tid & 15, b = tid >> 4;
            float s_ = boutp;
            #pragma unroll
            for (int cc = 0; cc < 4; ++cc) s_ += sOutP[cc][p][b];
            out[((size_t)(pb0 + b) * TT + (t + 2)) * PP + p0 + p] = s_;
        }
        if (wid >= 4) asm volatile("s_waitcnt vmcnt(0)" ::: "memory");
        __syncthreads();
        if (tid == 0) STA32(&flags[g * 16], kk);

        u64 igr = 0;
        if (tid < 384) igr = *(const u64*)(igbase + ((size_t)t * 64 + g) * 3072 + tid * 8);

        for (;;) {
            u32 v = LDA32(&flags[lane * 16]);
            if (__all((int)(v - kk) >= 0)) break;
            __builtin_amdgcn_s_sleep(1);
        }
        asm volatile("" ::: "memory");

        if (wid < 8) {
            const int kq = wid & 3;
            f32x4 c0 = {0.f,0.f,0.f,0.f}, c1 = {0.f,0.f,0.f,0.f}, c2 = {0.f,0.f,0.f,0.f};
            #pragma unroll
            for (int s = 0; s < 8; ++s) {
                const int ss = kq * 8 + s;
                const u64 q0 = LDA64(&hcur[2 * (ss * 128 + fo_hh)]);
                const u64 q1 = LDA64(&hcur[2 * (ss * 128 + fo_hh) + 1]);
                union { u64 q[2]; short8 v; } uu; uu.q[0] = q0; uu.q[1] = q1;
                c0 = __builtin_amdgcn_mfma_f32_16x16x32_bf16(frag[s],      uu.v, c0, 0, 0, 0);
                c1 = __builtin_amdgcn_mfma_f32_16x16x32_bf16(frag[8 + s],  uu.v, c1, 0, 0, 0);
                c2 = __builtin_amdgcn_mfma_f32_16x16x32_bf16(frag[16 + s], uu.v, c2, 0, 0, 0);
            }
            const int bt = wid >> 2, r0 = (lane >> 4) * 4, col = lane & 15;
            #pragma unroll
            for (int r = 0; r < 4; ++r) {
                sPreH[kq][r0 + r][bt][col]      = c0[r];
                sPreH[kq][16 + r0 + r][bt][col] = c1[r];
                sPreH[kq][32 + r0 + r][bt][col] = c2[r];
            }
        } else {
            const int kq3 = wid - 8;
            f32x4 d = {0.f, 0.f, 0.f, 0.f};
            #pragma unroll
            for (int s = 0; s < 8; ++s) {
                const int ss = kq3 * 8 + s;
                const u64 q0 = LDA64(&hcur[2 * (ss * 128 + fo_p3)]);
                const u64 q1 = LDA64(&hcur[2 * (ss * 128 + fo_p3) + 1]);
                union { u64 q[2]; short8 v; } uu; uu.q[0] = q0; uu.q[1] = q1;
                d = __builtin_amdgcn_mfma_f32_16x16x32_bf16(frag[s], uu.v, d, 0, 0, 0);
            }
            const int r0 = (lane >> 4) * 4, col = lane & 15;
            #pragma unroll
            for (int r = 0; r < 4; ++r) sOutP[kq3][r0 + r][col] = d[r];
        }
        if (tid < 384) sIgRaw[tid] = igr;
        __syncthreads();

        if (tid >= 256) {
            const u16* sIgU = (const u16*)sIgRaw;
            const float ig_r = bf2f(sIgU[gb * 48 + gwl]);
            const float ig_z = bf2f(sIgU[gb * 48 + 16 + gwl]);
            const float ig_n = bf2f(sIgU[gb * 48 + 32 + gwl]);
            const int bh = gb >> 4, bc = gb & 15;
            const float hg_r = sPreH[0][gwl][bh][bc] + sPreH[1][gwl][bh][bc]
                             + sPreH[2][gwl][bh][bc] + sPreH[3][gwl][bh][bc];
            const float hg_z = sPreH[0][16 + gwl][bh][bc] + sPreH[1][16 + gwl][bh][bc]
                             + sPreH[2][16 + gwl][bh][bc] + sPreH[3][16 + gwl][bh][bc];
            const float hg_n = sPreH[0][32 + gwl][bh][bc] + sPreH[1][32 + gwl][bh][bc]
                             + sPreH[2][32 + gwl][bh][bc] + sPreH[3][32 + gwl][bh][bc];
            const float rr = __builtin_amdgcn_rcpf(1.f + __expf(-(ig_r + hg_r)));
            const float zz = __builtin_amdgcn_rcpf(1.f + __expf(-(ig_z + hg_z)));
            const float xn = ig_n + rr * (hg_n + bnv);
            const float nn = 2.f * __builtin_amdgcn_rcpf(1.f + __expf(-2.f * xn)) - 1.f;
            h_own = nn + zz * (h_own - nn);
            STA16(&((u16*)hnxt)[hidx16], (u16)bfround(h_own));
        }

        u64* tmp = hcur; hcur = hnxt; hnxt = tmp;
        ++kk;
    }

    if (tid < 256) {
        const int p = tid & 15, b = tid >> 4;
        float s_ = boutp;
        #pragma unroll
        for (int cc = 0; cc < 4; ++cc) s_ += sOutP[cc][p][b];
        out[((size_t)(pb0 + b) * TT + 1) * PP + p0 + p] = s_;
    }
    if (wid >= 4) asm volatile("s_waitcnt vmcnt(0)" ::: "memory");
    __syncthreads();
    if (tid == 0) STA32(&flags[g * 16], kk);
    if (wid >= 8) {
        for (;;) {
            u32 v = LDA32(&flags[lane * 16]);
            if (__all((int)(v - kk) >= 0)) break;
            __builtin_amdgcn_s_sleep(1);
        }
        asm volatile("" ::: "memory");
        const int kq3 = wid - 8;
        f32x4 d = {0.f, 0.f, 0.f, 0.f};
        #pragma unroll
        for (int s = 0; s < 8; ++s) {
            const int ss = kq3 * 8 + s;
            const u64 q0 = LDA64(&hcur[2 * (ss * 128 + fo_p3)]);
            const u64 q1 = LDA64(&hcur[2 * (ss * 128 + fo_p3) + 1]);
            union { u64 q[2]; short8 v; } uu; uu.q[0] = q0; uu.q[1] = q1;
            d = __builtin_amdgcn_mfma_f32_16x16x32_bf16(frag[s], uu.v, d, 0, 0, 0);
        }
        const int r0 = (lane >> 4) * 4, col = lane & 15;
        #pragma unroll
        for (int r = 0; r < 4; ++r) sOutP[kq3][r0 + r][col] = d[r];
    }
    __syncthreads();
    if (tid < 256) {
        const int p = tid & 15, b = tid >> 4;
        const float s_ = boutp + sOutP[0][p][b] + sOutP[1][p][b]
                               + sOutP[2][p][b] + sOutP[3][p][b];
        out[((size_t)(pb0 + b) * TT) * PP + p0 + p] = s_;
    }
}

extern "C" void kernel_launch(void* const* d_in, const int* in_sizes, int n_in,
                              void* d_out, int out_size, void* d_ws, size_t ws_size,
                              hipStream_t stream) {
    const float* a      = (const float*)d_in[0];
    const float* h0     = (const float*)d_in[1];
    const float* Wih    = (const float*)d_in[2];
    const float* Whh    = (const float*)d_in[3];
    const float* bias   = (const float*)d_in[4];
    const float* bias_n = (const float*)d_in[5];
    const float* Wout   = (const float*)d_in[6];
    const float* bout   = (const float*)d_in[7];
    float* out = (float*)d_out;

    const size_t IG_BYTES  = (size_t)TT * 64 * 3072;       // 805,306,368
    const size_t NEED      = IG_BYTES + 2 * 65536 + 8192;

    if (ws_size >= NEED) {
        char* igbase  = (char*)d_ws;
        u64*  bufA    = (u64*)((char*)d_ws + IG_BYTES);
        u64*  bufB    = bufA + 8192;
        u32*  flags   = (u32*)((char*)d_ws + IG_BYTES + 2 * 65536);
        u32*  igready = flags + 1024;                      // second 4KB
        hipMemsetAsync(flags, 0, 8192, stream);
        void* args[] = {(void*)&a, (void*)&h0, (void*)&Wih, (void*)&Whh,
                        (void*)&bias, (void*)&bias_n, (void*)&Wout, (void*)&bout,
                        (void*)&igbase, (void*)&out,
                        (void*)&bufA, (void*)&bufB, (void*)&flags, (void*)&igready};
        hipLaunchCooperativeKernel((void*)gru_fused2, dim3(256), dim3(768),
                                   args, 0, stream);
    } else {
        // sequential mid-tier (proven): prepass16 then scan4
        char* igbase = (char*)d_ws;
        u64*  bufA   = (u64*)((char*)d_ws + IG_BYTES);
        u64*  bufB   = bufA + 8192;
        u32*  flags  = (u32*)((char*)d_ws + IG_BYTES + 2 * 65536);
        hipMemsetAsync(flags, 0, 4096, stream);
        hipLaunchKernelGGL(ig_prepass16, dim3(16, 64), dim3(768), 0, stream,
                           a, Wih, bias, igbase);
        void* args[] = {(void*)&h0, (void*)&Whh, (void*)&bias_n, (void*)&Wout,
                        (void*)&bout, (void*)&igbase, (void*)&out,
                        (void*)&bufA, (void*)&bufB, (void*)&flags};
        hipLaunchCooperativeKernel((void*)gru_scan4, dim3(64), dim3(768),
                                   args, 0, stream);
    }
}

// Round 15
// 17001.645 us; speedup vs baseline: 1.7127x; 1.0024x over previous
//
#include <hip/hip_runtime.h>
#include <cstddef>

#define TT 4096
#define PP 512
#define WW 1024

using u32 = unsigned;
using u64 = unsigned long long;
using u16 = unsigned short;

typedef short short8 __attribute__((ext_vector_type(8)));
typedef float f32x4 __attribute__((ext_vector_type(4)));

__device__ __forceinline__ u32 bfround(float f) {
    u32 u = __float_as_uint(f);
    return (u + 0x7fffu + ((u >> 16) & 1u)) >> 16;
}
__device__ __forceinline__ float bf2f(u32 q) { return __uint_as_float(q << 16); }
__device__ __forceinline__ float bflo(u32 q) { return __uint_as_float(q << 16); }
__device__ __forceinline__ float bfhi(u32 q) { return __uint_as_float(q & 0xffff0000u); }

#define LDA64(p)    __hip_atomic_load((p),  __ATOMIC_RELAXED, __HIP_MEMORY_SCOPE_AGENT)
#define STA64(p, v) __hip_atomic_store((p), (v), __ATOMIC_RELAXED, __HIP_MEMORY_SCOPE_AGENT)
#define LDA32(p)    __hip_atomic_load((p),  __ATOMIC_RELAXED, __HIP_MEMORY_SCOPE_AGENT)
#define STA32(p, v) __hip_atomic_store((p), (v), __ATOMIC_RELAXED, __HIP_MEMORY_SCOPE_AGENT)
#define STA16(p, v) __hip_atomic_store((p), (v), __ATOMIC_RELAXED, __HIP_MEMORY_SCOPE_AGENT)

// ===================== FUSED: scan4 role (WGs 0-63) + prepass role (WGs 64-255) =====================
// ig layout: u16[((t*64 + gWG)*32 + b)*48 + slot], slot = gate*16 + (w&15)
union SMemF {
    struct {                                  // scan role
        float sPreH[4][48][2][17];
        float sOutP[4][16][18];
        u64   sIgRaw[384];
    } s;
    struct {                                  // prepass role
        u16 aLds[32][520];
        u16 sIgT[8][32][48];
    } p;
};

__global__ __launch_bounds__(768, 1) void gru_fused2(
    const float* __restrict__ a, const float* __restrict__ h0v,
    const float* __restrict__ Wih, const float* __restrict__ Whh,
    const float* __restrict__ bias, const float* __restrict__ bias_n,
    const float* __restrict__ Wout, const float* __restrict__ bout,
    char* __restrict__ igbase, float* __restrict__ out,
    u64* __restrict__ bufA, u64* __restrict__ bufB,
    u32* __restrict__ flags, u32* __restrict__ igready)
{
    __shared__ __align__(16) SMemF sm;

    const int bid  = blockIdx.x;
    const int tid  = threadIdx.x;
    const int lane = tid & 63;
    const int wid  = tid >> 6;
    const int lq   = lane >> 4;
    const int bcol = lane & 15;

    if (bid < 64) {
        // ======================= SCAN ROLE =======================
        const int g   = bid;
        const int p0  = (g >> 1) * 16;
        const int pb0 = (g & 1) * 16;

        short8 frag[24];
        if (wid < 8) {
            const int kq = wid & 3;
            #pragma unroll
            for (int gate = 0; gate < 3; ++gate)
                #pragma unroll
                for (int s = 0; s < 8; ++s) {
                    const float* wr = &Whh[(size_t)(gate * WW + g * 16 + bcol) * WW
                                           + (kq * 8 + s) * 32 + lq * 8];
                    float t8[8];
                    *(float4*)&t8[0] = *(const float4*)&wr[0];
                    *(float4*)&t8[4] = *(const float4*)&wr[4];
                    short8 v;
                    #pragma unroll
                    for (int j = 0; j < 8; ++j) v[j] = (short)bfround(t8[j]);
                    frag[gate * 8 + s] = v;
                }
        } else {
            const int kq3 = wid - 8;
            #pragma unroll
            for (int s = 0; s < 8; ++s) {
                const float* wr = &Wout[(size_t)(p0 + bcol) * WW + (kq3 * 8 + s) * 32 + lq * 8];
                float t8[8];
                *(float4*)&t8[0] = *(const float4*)&wr[0];
                *(float4*)&t8[4] = *(const float4*)&wr[4];
                short8 v;
                #pragma unroll
                for (int j = 0; j < 8; ++j) v[j] = (short)bfround(t8[j]);
                frag[s] = v;
            }
        }

        float h_own = 0.f, bnv = 0.f;
        int gwl = 0, gb = 0; u32 hidx16 = 0;
        if (tid >= 256) {
            const int idx = tid - 256;
            gwl = idx & 15; gb = idx >> 4;
            h_own = h0v[g * 16 + gwl];
            bnv   = bias_n[g * 16 + gwl];
            const int w_abs = g * 16 + gwl;
            const int ip = (w_abs >> 3) * 64 + 2 * gb + ((w_abs >> 2) & 1);
            hidx16 = 4 * ip + (w_abs & 3);
            STA16(&((u16*)bufA)[hidx16], (u16)bfround(h_own));
        }
        const float boutp = (tid < 256) ? bout[p0 + (tid & 15)] : 0.f;

        const int fo_hh = lq * 32 + ((wid >> 2) & 1) * 16 + bcol;
        const int fo_p3 = lq * 32 + pb0 + bcol;

        u64* hcur = bufA;
        u64* hnxt = bufB;
        u32 kk = 1;

        for (int t = TT - 1; t >= 0; --t) {
            if (t < TT - 2 && tid < 256) {
                const int p = tid & 15, b = tid >> 4;
                float s_ = boutp;
                #pragma unroll
                for (int cc = 0; cc < 4; ++cc) s_ += sm.s.sOutP[cc][p][b];
                __builtin_nontemporal_store(s_,
                    &out[((size_t)(pb0 + b) * TT + (t + 2)) * PP + p0 + p]);
            }
            if (wid >= 4) asm volatile("s_waitcnt vmcnt(0)" ::: "memory");
            __syncthreads();
            if (tid == 0) STA32(&flags[g * 16], kk);

            // chunk gate (once per 64 steps)
            if ((t & 63) == 63 && tid < 384) {
                while (LDA32(&igready[(t >> 6) * 16]) < 8u)
                    __builtin_amdgcn_s_sleep(8);
            }
            u64 igr = 0;
            if (tid < 384) igr = *(const u64*)(igbase + ((size_t)t * 64 + g) * 3072 + tid * 8);

            for (;;) {
                u32 v = LDA32(&flags[lane * 16]);
                if (__all((int)(v - kk) >= 0)) break;
                __builtin_amdgcn_s_sleep(1);
            }
            asm volatile("" ::: "memory");

            if (wid < 8) {
                const int kq = wid & 3;
                f32x4 c0 = {0.f,0.f,0.f,0.f}, c1 = {0.f,0.f,0.f,0.f}, c2 = {0.f,0.f,0.f,0.f};
                #pragma unroll
                for (int s = 0; s < 8; ++s) {
                    const int ss = kq * 8 + s;
                    const u64 q0 = LDA64(&hcur[2 * (ss * 128 + fo_hh)]);
                    const u64 q1 = LDA64(&hcur[2 * (ss * 128 + fo_hh) + 1]);
                    union { u64 q[2]; short8 v; } uu; uu.q[0] = q0; uu.q[1] = q1;
                    c0 = __builtin_amdgcn_mfma_f32_16x16x32_bf16(frag[s],      uu.v, c0, 0, 0, 0);
                    c1 = __builtin_amdgcn_mfma_f32_16x16x32_bf16(frag[8 + s],  uu.v, c1, 0, 0, 0);
                    c2 = __builtin_amdgcn_mfma_f32_16x16x32_bf16(frag[16 + s], uu.v, c2, 0, 0, 0);
                }
                const int bt = wid >> 2, r0 = lq * 4;
                #pragma unroll
                for (int r = 0; r < 4; ++r) {
                    sm.s.sPreH[kq][r0 + r][bt][bcol]      = c0[r];
                    sm.s.sPreH[kq][16 + r0 + r][bt][bcol] = c1[r];
                    sm.s.sPreH[kq][32 + r0 + r][bt][bcol] = c2[r];
                }
            } else {
                const int kq3 = wid - 8;
                f32x4 d = {0.f, 0.f, 0.f, 0.f};
                #pragma unroll
                for (int s = 0; s < 8; ++s) {
                    const int ss = kq3 * 8 + s;
                    const u64 q0 = LDA64(&hcur[2 * (ss * 128 + fo_p3)]);
                    const u64 q1 = LDA64(&hcur[2 * (ss * 128 + fo_p3) + 1]);
                    union { u64 q[2]; short8 v; } uu; uu.q[0] = q0; uu.q[1] = q1;
                    d = __builtin_amdgcn_mfma_f32_16x16x32_bf16(frag[s], uu.v, d, 0, 0, 0);
                }
                const int r0 = lq * 4;
                #pragma unroll
                for (int r = 0; r < 4; ++r) sm.s.sOutP[kq3][r0 + r][bcol] = d[r];
            }
            if (tid < 384) sm.s.sIgRaw[tid] = igr;
            __syncthreads();

            if (tid >= 256) {
                const u16* sIgU = (const u16*)sm.s.sIgRaw;
                const float ig_r = bf2f(sIgU[gb * 48 + gwl]);
                const float ig_z = bf2f(sIgU[gb * 48 + 16 + gwl]);
                const float ig_n = bf2f(sIgU[gb * 48 + 32 + gwl]);
                const int bh = gb >> 4, bc = gb & 15;
                const float hg_r = sm.s.sPreH[0][gwl][bh][bc] + sm.s.sPreH[1][gwl][bh][bc]
                                 + sm.s.sPreH[2][gwl][bh][bc] + sm.s.sPreH[3][gwl][bh][bc];
                const float hg_z = sm.s.sPreH[0][16 + gwl][bh][bc] + sm.s.sPreH[1][16 + gwl][bh][bc]
                                 + sm.s.sPreH[2][16 + gwl][bh][bc] + sm.s.sPreH[3][16 + gwl][bh][bc];
                const float hg_n = sm.s.sPreH[0][32 + gwl][bh][bc] + sm.s.sPreH[1][32 + gwl][bh][bc]
                                 + sm.s.sPreH[2][32 + gwl][bh][bc] + sm.s.sPreH[3][32 + gwl][bh][bc];
                const float rr = __builtin_amdgcn_rcpf(1.f + __expf(-(ig_r + hg_r)));
                const float zz = __builtin_amdgcn_rcpf(1.f + __expf(-(ig_z + hg_z)));
                const float xn = ig_n + rr * (hg_n + bnv);
                const float nn = 2.f * __builtin_amdgcn_rcpf(1.f + __expf(-2.f * xn)) - 1.f;
                h_own = nn + zz * (h_own - nn);
                STA16(&((u16*)hnxt)[hidx16], (u16)bfround(h_own));
            }

            u64* tmp = hcur; hcur = hnxt; hnxt = tmp;
            ++kk;
        }

        // epilogue: out[1] from t=0 iteration's sOutP, then s_0 -> out[:,0,:]
        if (tid < 256) {
            const int p = tid & 15, b = tid >> 4;
            float s_ = boutp;
            #pragma unroll
            for (int cc = 0; cc < 4; ++cc) s_ += sm.s.sOutP[cc][p][b];
            out[((size_t)(pb0 + b) * TT + 1) * PP + p0 + p] = s_;
        }
        if (wid >= 4) asm volatile("s_waitcnt vmcnt(0)" ::: "memory");
        __syncthreads();
        if (tid == 0) STA32(&flags[g * 16], kk);
        if (wid >= 8) {
            for (;;) {
                u32 v = LDA32(&flags[lane * 16]);
                if (__all((int)(v - kk) >= 0)) break;
                __builtin_amdgcn_s_sleep(1);
            }
            asm volatile("" ::: "memory");
            const int kq3 = wid - 8;
            f32x4 d = {0.f, 0.f, 0.f, 0.f};
            #pragma unroll
            for (int s = 0; s < 8; ++s) {
                const int ss = kq3 * 8 + s;
                const u64 q0 = LDA64(&hcur[2 * (ss * 128 + fo_p3)]);
                const u64 q1 = LDA64(&hcur[2 * (ss * 128 + fo_p3) + 1]);
                union { u64 q[2]; short8 v; } uu; uu.q[0] = q0; uu.q[1] = q1;
                d = __builtin_amdgcn_mfma_f32_16x16x32_bf16(frag[s], uu.v, d, 0, 0, 0);
            }
            const int r0 = lq * 4;
            #pragma unroll
            for (int r = 0; r < 4; ++r) sm.s.sOutP[kq3][r0 + r][bcol] = d[r];
        }
        __syncthreads();
        if (tid < 256) {
            const int p = tid & 15, b = tid >> 4;
            const float s_ = boutp + sm.s.sOutP[0][p][b] + sm.s.sOutP[1][p][b]
                                   + sm.s.sOutP[2][p][b] + sm.s.sOutP[3][p][b];
            out[((size_t)(pb0 + b) * TT) * PP + p0 + p] = s_;
        }
    } else {
        // ======================= PREPASS ROLE =======================
        const int pid = bid - 64;                 // 0..191
        for (int vb = pid; vb < 512; vb += 192) {
            const int j  = vb & 7;
            const int tb = 63 - (vb >> 3);        // reverse-t chunks first

            short8 af[2][16];
            float  bi[2][4];
            #pragma unroll
            for (int rt = 0; rt < 2; ++rt) {
                const int ti = wid * 2 + rt;
                const int gate_t = ti >> 3, gl_t = ti & 7;
                const int rowb = gate_t * WW + j * 128 + gl_t * 16;
                const float* wr = &Wih[(size_t)(rowb + bcol) * PP + lq * 8];
                #pragma unroll
                for (int s = 0; s < 16; ++s) {
                    float t8[8];
                    *(float4*)&t8[0] = *(const float4*)&wr[s * 32];
                    *(float4*)&t8[4] = *(const float4*)&wr[s * 32 + 4];
                    #pragma unroll
                    for (int jj = 0; jj < 8; ++jj) af[rt][s][jj] = (short)bfround(t8[jj]);
                }
                #pragma unroll
                for (int r = 0; r < 4; ++r) bi[rt][r] = bias[rowb + lq * 4 + r];
            }

            for (int tt = 0; tt < 64; ++tt) {
                const int t = tb * 64 + tt;
                // stage a_t -> LDS bf16 (nontemporal reads: stream, don't pollute L2/L3)
                for (int i = tid; i < 2048; i += 768) {
                    const int b = i >> 6, oct = i & 63;
                    const float* ap = &a[((size_t)b * TT + t) * PP + oct * 8];
                    f32x4 f0 = __builtin_nontemporal_load((const f32x4*)ap);
                    f32x4 f1 = __builtin_nontemporal_load(((const f32x4*)ap) + 1);
                    uint2 w0, w1;
                    w0.x = bfround(f0[0]) | (bfround(f0[1]) << 16);
                    w0.y = bfround(f0[2]) | (bfround(f0[3]) << 16);
                    w1.x = bfround(f1[0]) | (bfround(f1[1]) << 16);
                    w1.y = bfround(f1[2]) | (bfround(f1[3]) << 16);
                    *(uint2*)&sm.p.aLds[b][oct * 8]     = w0;
                    *(uint2*)&sm.p.aLds[b][oct * 8 + 4] = w1;
                }
                __syncthreads();
                #pragma unroll
                for (int rt = 0; rt < 2; ++rt) {
                    const int ti = wid * 2 + rt;
                    const int gate_t = ti >> 3, gl_t = ti & 7;
                    #pragma unroll
                    for (int bh = 0; bh < 2; ++bh) {
                        f32x4 d = {0.f, 0.f, 0.f, 0.f};
                        #pragma unroll 4
                        for (int s = 0; s < 16; ++s) {
                            short8 bf = *(const short8*)&sm.p.aLds[bh * 16 + bcol][s * 32 + lq * 8];
                            d = __builtin_amdgcn_mfma_f32_16x16x32_bf16(af[rt][s], bf, d, 0, 0, 0);
                        }
                        u32 lo = bfround(d[0] + bi[rt][0]) | (bfround(d[1] + bi[rt][1]) << 16);
                        u32 hi = bfround(d[2] + bi[rt][2]) | (bfround(d[3] + bi[rt][3]) << 16);
                        *(u64*)&sm.p.sIgT[gl_t][bh * 16 + bcol][gate_t * 16 + lq * 4] =
                            (u64)lo | ((u64)hi << 32);
                    }
                }
                __syncthreads();
                {
                    const u64* src = (const u64*)sm.p.sIgT;
                    u64* dst = (u64*)(igbase + ((size_t)t * 64 + j * 8) * 3072);
                    #pragma unroll
                    for (int r = 0; r < 4; ++r) STA64(&dst[r * 768 + tid], src[r * 768 + tid]);
                }
                __syncthreads();
            }
            asm volatile("s_waitcnt vmcnt(0)" ::: "memory");
            __syncthreads();
            if (tid == 0)
                __hip_atomic_fetch_add(&igready[tb * 16], 1u,
                                       __ATOMIC_RELAXED, __HIP_MEMORY_SCOPE_AGENT);
        }
    }
}

// ============ PREPASS v2 (mid-tier, f32 a, proven) ============
__global__ __launch_bounds__(768, 1) void ig_prepass16(
    const float* __restrict__ a, const float* __restrict__ Wih,
    const float* __restrict__ bias, char* __restrict__ igbase)
{
    const int gp   = blockIdx.x;
    const int t0   = blockIdx.y * 64;
    const int tid  = threadIdx.x;
    const int lane = tid & 63;
    const int wid  = tid >> 6;
    const int growb = gp * 192 + wid * 16;

    short8 afrag[16];
    float  biasv[4];
    {
        const float* wr = &Wih[(size_t)(growb + (lane & 15)) * PP + (lane >> 4) * 8];
        #pragma unroll
        for (int s = 0; s < 16; ++s) {
            float t8[8];
            *(float4*)&t8[0] = *(const float4*)&wr[s * 32];
            *(float4*)&t8[4] = *(const float4*)&wr[s * 32 + 4];
            #pragma unroll
            for (int j = 0; j < 8; ++j) afrag[s][j] = (short)bfround(t8[j]);
        }
        #pragma unroll
        for (int r = 0; r < 4; ++r) biasv[r] = bias[growb + (lane >> 4) * 4 + r];
    }
    const int grow0 = growb + (lane >> 4) * 4;
    const int gate  = grow0 >> 10;
    const int w     = grow0 & 1023;
    const int gWG   = w >> 4;
    const int slot  = gate * 16 + (w & 15);
    const int bcol  = lane & 15;

    for (int ct = 0; ct < 128; ++ct) {
        const int t = t0 + (ct >> 1);
        const int b = (ct & 1) * 16 + bcol;
        const float* ap = &a[((size_t)b * TT + t) * PP + (lane >> 4) * 8];
        f32x4 d = {0.f, 0.f, 0.f, 0.f};
        #pragma unroll 4
        for (int s = 0; s < 16; ++s) {
            float4 lo = *(const float4*)&ap[s * 32];
            float4 hi = *(const float4*)&ap[s * 32 + 4];
            short8 bfv;
            bfv[0] = (short)((__float_as_uint(lo.x) + 0x8000u) >> 16);
            bfv[1] = (short)((__float_as_uint(lo.y) + 0x8000u) >> 16);
            bfv[2] = (short)((__float_as_uint(lo.z) + 0x8000u) >> 16);
            bfv[3] = (short)((__float_as_uint(lo.w) + 0x8000u) >> 16);
            bfv[4] = (short)((__float_as_uint(hi.x) + 0x8000u) >> 16);
            bfv[5] = (short)((__float_as_uint(hi.y) + 0x8000u) >> 16);
            bfv[6] = (short)((__float_as_uint(hi.z) + 0x8000u) >> 16);
            bfv[7] = (short)((__float_as_uint(hi.w) + 0x8000u) >> 16);
            d = __builtin_amdgcn_mfma_f32_16x16x32_bf16(afrag[s], bfv, d, 0, 0, 0);
        }
        u32 lo32 = bfround(d[0] + biasv[0]) | (bfround(d[1] + biasv[1]) << 16);
        u32 hi32 = bfround(d[2] + biasv[2]) | (bfround(d[3] + biasv[3]) << 16);
        *(u64*)(igbase + (((size_t)t * 64 + gWG) * 1536 + (size_t)b * 48 + slot) * 2) =
            (u64)lo32 | ((u64)hi32 << 32);
    }
}

// ============ SCAN v4 standalone (mid-tier, proven 15.3 ms) ============
__global__ __launch_bounds__(768, 1) void gru_scan4(
    const float* __restrict__ h0v, const float* __restrict__ Whh,
    const float* __restrict__ bias_n, const float* __restrict__ Wout,
    const float* __restrict__ bout, const char* __restrict__ igbase,
    float* __restrict__ out, u64* __restrict__ bufA, u64* __restrict__ bufB,
    u32* __restrict__ flags)
{
    __shared__ float sPreH[4][48][2][17];
    __shared__ float sOutP[4][16][18];
    __shared__ __align__(8) u64 sIgRaw[384];

    const int g    = blockIdx.x;
    const int tid  = threadIdx.x;
    const int lane = tid & 63;
    const int wid  = tid >> 6;
    const int p0   = (g >> 1) * 16;
    const int pb0  = (g & 1) * 16;

    short8 frag[24];
    if (wid < 8) {
        const int kq = wid & 3;
        #pragma unroll
        for (int gate = 0; gate < 3; ++gate)
            #pragma unroll
            for (int s = 0; s < 8; ++s) {
                const float* wr = &Whh[(size_t)(gate * WW + g * 16 + (lane & 15)) * WW
                                       + (kq * 8 + s) * 32 + (lane >> 4) * 8];
                float t8[8];
                *(float4*)&t8[0] = *(const float4*)&wr[0];
                *(float4*)&t8[4] = *(const float4*)&wr[4];
                short8 v;
                #pragma unroll
                for (int j = 0; j < 8; ++j) v[j] = (short)bfround(t8[j]);
                frag[gate * 8 + s] = v;
            }
    } else {
        const int kq3 = wid - 8;
        #pragma unroll
        for (int s = 0; s < 8; ++s) {
            const float* wr = &Wout[(size_t)(p0 + (lane & 15)) * WW
                                    + (kq3 * 8 + s) * 32 + (lane >> 4) * 8];
            float t8[8];
            *(float4*)&t8[0] = *(const float4*)&wr[0];
            *(float4*)&t8[4] = *(const float4*)&wr[4];
            short8 v;
            #pragma unroll
            for (int j = 0; j < 8; ++j) v[j] = (short)bfround(t8[j]);
            frag[s] = v;
        }
    }

    float h_own = 0.f, bnv = 0.f;
    int gwl = 0, gb = 0; u32 hidx16 = 0;
    if (tid >= 256) {
        const int idx = tid - 256;
        gwl = idx & 15; gb = idx >> 4;
        h_own = h0v[g * 16 + gwl];
        bnv   = bias_n[g * 16 + gwl];
        const int w_abs = g * 16 + gwl;
        const int ip = (w_abs >> 3) * 64 + 2 * gb + ((w_abs >> 2) & 1);
        hidx16 = 4 * ip + (w_abs & 3);
        STA16(&((u16*)bufA)[hidx16], (u16)bfround(h_own));
    }
    const float boutp = (tid < 256) ? bout[p0 + (tid & 15)] : 0.f;

    const int fo_hh = (lane >> 4) * 32 + ((wid >> 2) & 1) * 16 + (lane & 15);
    const int fo_p3 = (lane >> 4) * 32 + pb0 + (lane & 15);

    u64* hcur = bufA;
    u64* hnxt = bufB;
    u32 kk = 1;

    for (int t = TT - 1; t >= 0; --t) {
        if (t < TT - 2 && tid < 256) {
            const int p = tid & 15, b = tid >> 4;
            float s_ = boutp;
            #pragma unroll
            for (int cc = 0; cc < 4; ++cc) s_ += sOutP[cc][p][b];
            out[((size_t)(pb0 + b) * TT + (t + 2)) * PP + p0 + p] = s_;
        }
        if (wid >= 4) asm volatile("s_waitcnt vmcnt(0)" ::: "memory");
        __syncthreads();
        if (tid == 0) STA32(&flags[g * 16], kk);

        u64 igr = 0;
        if (tid < 384) igr = *(const u64*)(igbase + ((size_t)t * 64 + g) * 3072 + tid * 8);

        for (;;) {
            u32 v = LDA32(&flags[lane * 16]);
            if (__all((int)(v - kk) >= 0)) break;
            __builtin_amdgcn_s_sleep(1);
        }
        asm volatile("" ::: "memory");

        if (wid < 8) {
            const int kq = wid & 3;
            f32x4 c0 = {0.f,0.f,0.f,0.f}, c1 = {0.f,0.f,0.f,0.f}, c2 = {0.f,0.f,0.f,0.f};
            #pragma unroll
            for (int s = 0; s < 8; ++s) {
                const int ss = kq * 8 + s;
                const u64 q0 = LDA64(&hcur[2 * (ss * 128 + fo_hh)]);
                const u64 q1 = LDA64(&hcur[2 * (ss * 128 + fo_hh) + 1]);
                union { u64 q[2]; short8 v; } uu; uu.q[0] = q0; uu.q[1] = q1;
                c0 = __builtin_amdgcn_mfma_f32_16x16x32_bf16(frag[s],      uu.v, c0, 0, 0, 0);
                c1 = __builtin_amdgcn_mfma_f32_16x16x32_bf16(frag[8 + s],  uu.v, c1, 0, 0, 0);
                c2 = __builtin_amdgcn_mfma_f32_16x16x32_bf16(frag[16 + s], uu.v, c2, 0, 0, 0);
            }
            const int bt = wid >> 2, r0 = (lane >> 4) * 4, col = lane & 15;
            #pragma unroll
            for (int r = 0; r < 4; ++r) {
                sPreH[kq][r0 + r][bt][col]      = c0[r];
                sPreH[kq][16 + r0 + r][bt][col] = c1[r];
                sPreH[kq][32 + r0 + r][bt][col] = c2[r];
            }
        } else {
            const int kq3 = wid - 8;
            f32x4 d = {0.f, 0.f, 0.f, 0.f};
            #pragma unroll
            for (int s = 0; s < 8; ++s) {
                const int ss = kq3 * 8 + s;
                const u64 q0 = LDA64(&hcur[2 * (ss * 128 + fo_p3)]);
                const u64 q1 = LDA64(&hcur[2 * (ss * 128 + fo_p3) + 1]);
                union { u64 q[2]; short8 v; } uu; uu.q[0] = q0; uu.q[1] = q1;
                d = __builtin_amdgcn_mfma_f32_16x16x32_bf16(frag[s], uu.v, d, 0, 0, 0);
            }
            const int r0 = (lane >> 4) * 4, col = lane & 15;
            #pragma unroll
            for (int r = 0; r < 4; ++r) sOutP[kq3][r0 + r][col] = d[r];
        }
        if (tid < 384) sIgRaw[tid] = igr;
        __syncthreads();

        if (tid >= 256) {
            const u16* sIgU = (const u16*)sIgRaw;
            const float ig_r = bf2f(sIgU[gb * 48 + gwl]);
            const float ig_z = bf2f(sIgU[gb * 48 + 16 + gwl]);
            const float ig_n = bf2f(sIgU[gb * 48 + 32 + gwl]);
            const int bh = gb >> 4, bc = gb & 15;
            const float hg_r = sPreH[0][gwl][bh][bc] + sPreH[1][gwl][bh][bc]
                             + sPreH[2][gwl][bh][bc] + sPreH[3][gwl][bh][bc];
            const float hg_z = sPreH[0][16 + gwl][bh][bc] + sPreH[1][16 + gwl][bh][bc]
                             + sPreH[2][16 + gwl][bh][bc] + sPreH[3][16 + gwl][bh][bc];
            const float hg_n = sPreH[0][32 + gwl][bh][bc] + sPreH[1][32 + gwl][bh][bc]
                             + sPreH[2][32 + gwl][bh][bc] + sPreH[3][32 + gwl][bh][bc];
            const float rr = __builtin_amdgcn_rcpf(1.f + __expf(-(ig_r + hg_r)));
            const float zz = __builtin_amdgcn_rcpf(1.f + __expf(-(ig_z + hg_z)));
            const float xn = ig_n + rr * (hg_n + bnv);
            const float nn = 2.f * __builtin_amdgcn_rcpf(1.f + __expf(-2.f * xn)) - 1.f;
            h_own = nn + zz * (h_own - nn);
            STA16(&((u16*)hnxt)[hidx16], (u16)bfround(h_own));
        }

        u64* tmp = hcur; hcur = hnxt; hnxt = tmp;
        ++kk;
    }

    if (tid < 256) {
        const int p = tid & 15, b = tid >> 4;
        float s_ = boutp;
        #pragma unroll
        for (int cc = 0; cc < 4; ++cc) s_ += sOutP[cc][p][b];
        out[((size_t)(pb0 + b) * TT + 1) * PP + p0 + p] = s_;
    }
    if (wid >= 4) asm volatile("s_waitcnt vmcnt(0)" ::: "memory");
    __syncthreads();
    if (tid == 0) STA32(&flags[g * 16], kk);
    if (wid >= 8) {
        for (;;) {
            u32 v = LDA32(&flags[lane * 16]);
            if (__all((int)(v - kk) >= 0)) break;
            __builtin_amdgcn_s_sleep(1);
        }
        asm volatile("" ::: "memory");
        const int kq3 = wid - 8;
        f32x4 d = {0.f, 0.f, 0.f, 0.f};
        #pragma unroll
        for (int s = 0; s < 8; ++s) {
            const int ss = kq3 * 8 + s;
            const u64 q0 = LDA64(&hcur[2 * (ss * 128 + fo_p3)]);
            const u64 q1 = LDA64(&hcur[2 * (ss * 128 + fo_p3) + 1]);
            union { u64 q[2]; short8 v; } uu; uu.q[0] = q0; uu.q[1] = q1;
            d = __builtin_amdgcn_mfma_f32_16x16x32_bf16(frag[s], uu.v, d, 0, 0, 0);
        }
        const int r0 = (lane >> 4) * 4, col = lane & 15;
        #pragma unroll
        for (int r = 0; r < 4; ++r) sOutP[kq3][r0 + r][col] = d[r];
    }
    __syncthreads();
    if (tid < 256) {
        const int p = tid & 15, b = tid >> 4;
        const float s_ = boutp + sOutP[0][p][b] + sOutP[1][p][b]
                               + sOutP[2][p][b] + sOutP[3][p][b];
        out[((size_t)(pb0 + b) * TT) * PP + p0 + p] = s_;
    }
}

extern "C" void kernel_launch(void* const* d_in, const int* in_sizes, int n_in,
                              void* d_out, int out_size, void* d_ws, size_t ws_size,
                              hipStream_t stream) {
    const float* a      = (const float*)d_in[0];
    const float* h0     = (const float*)d_in[1];
    const float* Wih    = (const float*)d_in[2];
    const float* Whh    = (const float*)d_in[3];
    const float* bias   = (const float*)d_in[4];
    const float* bias_n = (const float*)d_in[5];
    const float* Wout   = (const float*)d_in[6];
    const float* bout   = (const float*)d_in[7];
    float* out = (float*)d_out;

    const size_t IG_BYTES  = (size_t)TT * 64 * 3072;       // 805,306,368
    const size_t NEED      = IG_BYTES + 2 * 65536 + 8192;

    if (ws_size >= NEED) {
        char* igbase  = (char*)d_ws;
        u64*  bufA    = (u64*)((char*)d_ws + IG_BYTES);
        u64*  bufB    = bufA + 8192;
        u32*  flags   = (u32*)((char*)d_ws + IG_BYTES + 2 * 65536);
        u32*  igready = flags + 1024;
        hipMemsetAsync(flags, 0, 8192, stream);
        void* args[] = {(void*)&a, (void*)&h0, (void*)&Wih, (void*)&Whh,
                        (void*)&bias, (void*)&bias_n, (void*)&Wout, (void*)&bout,
                        (void*)&igbase, (void*)&out,
                        (void*)&bufA, (void*)&bufB, (void*)&flags, (void*)&igready};
        hipLaunchCooperativeKernel((void*)gru_fused2, dim3(256), dim3(768),
                                   args, 0, stream);
    } else {
        char* igbase = (char*)d_ws;
        u64*  bufA   = (u64*)((char*)d_ws + IG_BYTES);
        u64*  bufB   = bufA + 8192;
        u32*  flags  = (u32*)((char*)d_ws + IG_BYTES + 2 * 65536);
        hipMemsetAsync(flags, 0, 4096, stream);
        hipLaunchKernelGGL(ig_prepass16, dim3(16, 64), dim3(768), 0, stream,
                           a, Wih, bias, igbase);
        void* args[] = {(void*)&h0, (void*)&Whh, (void*)&bias_n, (void*)&Wout,
                        (void*)&bout, (void*)&igbase, (void*)&out,
                        (void*)&bufA, (void*)&bufB, (void*)&flags};
        hipLaunchCooperativeKernel((void*)gru_scan4, dim3(64), dim3(768),
                                   args, 0, stream);
    }
}